// Round 13
// baseline (391.607 us; speedup 1.0000x reference)
//
#include <hip/hip_runtime.h>

// ---------------------------------------------------------------------------
// AttentionMulti: x[4,2048,1024] fp32 -> qkv -> 16-head attention (D=64,
// scale=0.5, key-mask) -> out proj.  Inputs/outputs fp32, mask int32.
// Internal compute in bf16 MFMA.
// ---------------------------------------------------------------------------

typedef __bf16 bf16;
typedef __attribute__((ext_vector_type(8))) __bf16 bf16x8;
typedef __attribute__((ext_vector_type(4))) float f32x4;

#define MFMA16(a, b, c) __builtin_amdgcn_mfma_f32_16x16x32_bf16(a, b, c, 0, 0, 0)
#define GLOAD_LDS(src, dst) __builtin_amdgcn_global_load_lds( \
    (const __attribute__((address_space(1))) void*)(src),     \
    (__attribute__((address_space(3))) void*)(dst), 16, 0, 0)
#define BAR() __builtin_amdgcn_s_barrier()
#define VMCNT(n) asm volatile("s_waitcnt vmcnt(" #n ")" ::: "memory")

// 0.5 * log2(e): folded into Q (w_qkv cols 0..1023 and b_qkv[0..1023])
#define QSCALE 0.72134752f

// ---------------------------------------------------------------------------
// Fused prologue: cvt x->bf16 (blocks 0..8191) || transpose w_qkv
// (blocks 8192..8959) || transpose w_out (blocks 8960..9215).
// ---------------------------------------------------------------------------
__device__ __forceinline__ void transpose_tile(
    const float* __restrict__ in, bf16* __restrict__ out, int R, int C,
    int scale_rows, float scale, int bx, int by, int t, float (*s)[65])
{
    const int r0 = by * 64;
    const int c0 = bx * 64;
    const int tr  = t >> 4;
    const int tc4 = (t & 15) * 4;
#pragma unroll
    for (int p = 0; p < 4; ++p) {
        int r = tr + p * 16;
        float4 v = *(const float4*)(in + (size_t)(r0 + r) * C + c0 + tc4);
        s[r][tc4 + 0] = v.x; s[r][tc4 + 1] = v.y;
        s[r][tc4 + 2] = v.z; s[r][tc4 + 3] = v.w;
    }
    __syncthreads();
    const int cw  = t >> 3;
    const int rw8 = (t & 7) * 8;
#pragma unroll
    for (int p = 0; p < 2; ++p) {
        int c = cw + p * 32;
        float f = (c0 + c) < scale_rows ? scale : 1.0f;
        union { uint4 v; bf16 h[8]; } u;
#pragma unroll
        for (int j = 0; j < 8; ++j) u.h[j] = (bf16)(s[rw8 + j][c] * f);
        *(uint4*)(out + (size_t)(c0 + c) * R + r0 + rw8) = u.v;
    }
}

__global__ __launch_bounds__(256, 1) void prep_kernel(
    const float* __restrict__ x, bf16* __restrict__ xb,
    const float* __restrict__ w_qkv, bf16* __restrict__ wqkvT,
    const float* __restrict__ w_out, bf16* __restrict__ woutT)
{
    __shared__ float s[64][65];
    const int t = threadIdx.x;
    int blk = blockIdx.x;
    if (blk < 8192) {
        int i = blk * 256 + t;
        float4 v = *(const float4*)(x + (size_t)i * 4);
        union { ushort4 u; bf16 h[4]; } o;
        o.h[0] = (bf16)v.x; o.h[1] = (bf16)v.y;
        o.h[2] = (bf16)v.z; o.h[3] = (bf16)v.w;
        *(ushort4*)(xb + (size_t)i * 4) = o.u;
        return;
    }
    blk -= 8192;
    if (blk < 768) {
        transpose_tile(w_qkv, wqkvT, 1024, 3072, 1024, QSCALE,
                       blk % 48, blk / 48, t, s);
    } else {
        blk -= 768;
        transpose_tile(w_out, woutT, 1024, 1024, 0, 1.0f,
                       blk % 16, blk / 16, t, s);
    }
}

// ---------------------------------------------------------------------------
// 128x256-tile GEMM, BK=64, 3-slot, 2 phases/K-tile (round-10 known-good).
// GEMM matrix fully explored (schedules x3, locality, occupancy, barriers):
// plateau ~440 TF.  r11 1-barrier merge: +13us (phase split = load balance).
// r12 3-blocks/CU BK=32: +3.5us (occupancy not the GEMM limiter).
// ---------------------------------------------------------------------------
template <typename OutT>
__global__ __launch_bounds__(512, 2) void gemm128x256_kernel(
    const bf16* __restrict__ A, const bf16* __restrict__ Bt,
    const float* __restrict__ bias, OutT* __restrict__ C,
    int M, int N, int K, int qcols, float qscale, int nbx)
{
    __shared__ __align__(16) bf16 As[3 * 128 * 64];   // 48 KiB
    __shared__ __align__(16) bf16 Bs[3 * 256 * 64];   // 96 KiB

    const int t    = threadIdx.x;
    const int lane = t & 63;
    const int wave = t >> 6;
    const int wr   = wave >> 2;
    const int wc   = wave & 3;
    const int l15  = lane & 15;
    const int g    = lane >> 4;

    const int nwg  = gridDim.x;
    const int per  = nwg >> 3;
    const int mper = per / nbx;
    const int wg   = blockIdx.x;
    const int xcd  = wg & 7;
    const int idx  = wg >> 3;
    const int m0   = (xcd * mper + idx % mper) * 128;
    const int n0   = (idx / mper) * 256;

    const int ntile = K >> 6;

    int srow[2], sblk[2];
#pragma unroll
    for (int r = 0; r < 2; ++r) {
        int s = t * 16 + r * 8192;
        srow[r] = s >> 7;
        int blk = (s >> 4) & 7;
        sblk[r] = blk ^ (srow[r] & 7);
    }
    const int ldst0 = t * 8;

    const bf16* Abase = A  + (size_t)m0 * K;
    const bf16* Bbase = Bt + (size_t)n0 * K;

    const f32x4 z = {0.f, 0.f, 0.f, 0.f};
    f32x4 acc[4][4];
#pragma unroll
    for (int i = 0; i < 4; ++i)
#pragma unroll
        for (int j = 0; j < 4; ++j) acc[i][j] = z;

    auto stageA = [&](int tile, int slot) {
        if (tile >= ntile) return;
        bf16* dst = As + slot * 8192;
        const bf16* src = Abase + tile * 64;
#pragma unroll
        for (int r = 0; r < 2; ++r)
            GLOAD_LDS(src + (size_t)srow[r] * K + sblk[r] * 8,
                      dst + ldst0 + r * 4096);
    };
    auto stageBh = [&](int tile, int slot, int h) {
        if (tile >= ntile) return;
        bf16* dst = Bs + slot * 16384 + h * 8192;
        const bf16* src = Bbase + (size_t)(h * 128) * K + tile * 64;
#pragma unroll
        for (int r = 0; r < 2; ++r)
            GLOAD_LDS(src + (size_t)srow[r] * K + sblk[r] * 8,
                      dst + ldst0 + r * 4096);
    };

#define LOAD_AF(slot)                                                         \
    _Pragma("unroll")                                                         \
    for (int f = 0; f < 4; ++f) {                                             \
        int row = wr * 64 + f * 16 + l15;                                     \
        _Pragma("unroll")                                                     \
        for (int ks = 0; ks < 2; ++ks)                                        \
            af[f][ks] = *(const bf16x8*)(&As[(slot) * 8192 + row * 64 +       \
                            (((ks * 4 + g) ^ (row & 7)) * 8)]);               \
    }
#define LOAD_BF(slot, half, dstv)                                             \
    _Pragma("unroll")                                                         \
    for (int c2 = 0; c2 < 2; ++c2) {                                          \
        int row = wc * 64 + ((half) * 2 + c2) * 16 + l15;                     \
        _Pragma("unroll")                                                     \
        for (int ks = 0; ks < 2; ++ks)                                        \
            dstv[c2][ks] = *(const bf16x8*)(&Bs[(slot) * 16384 + row * 64 +   \
                            (((ks * 4 + g) ^ (row & 7)) * 8)]);               \
    }
#define MFMA_H(bv, half)                                                      \
    {                                                                         \
        __builtin_amdgcn_s_setprio(1);                                        \
        _Pragma("unroll")                                                     \
        for (int f = 0; f < 4; ++f)                                           \
            _Pragma("unroll")                                                 \
            for (int c2 = 0; c2 < 2; ++c2) {                                  \
                acc[f][(half) * 2 + c2] = MFMA16(                             \
                    af[f][0], bv[c2][0], acc[f][(half) * 2 + c2]);            \
                acc[f][(half) * 2 + c2] = MFMA16(                             \
                    af[f][1], bv[c2][1], acc[f][(half) * 2 + c2]);            \
            }                                                                 \
        __builtin_amdgcn_s_setprio(0);                                        \
    }

    stageA(0, 0); stageBh(0, 0, 0); stageBh(0, 0, 1);
    stageA(1, 1); stageBh(1, 1, 0); stageBh(1, 1, 1);
    VMCNT(6);
    BAR();

    int slot = 0;
    for (int T = 0; T < ntile; ++T) {
        int slot2 = slot + 2; if (slot2 >= 3) slot2 -= 3;
        bf16x8 af[4][2], blo[2][2], bhi[2][2];
        LOAD_AF(slot);
        LOAD_BF(slot, 0, blo);
        stageA(T + 2, slot2);
        stageBh(T + 2, slot2, 0);
        MFMA_H(blo, 0);
        BAR();
        LOAD_BF(slot, 1, bhi);
        stageBh(T + 2, slot2, 1);
        MFMA_H(bhi, 1);
        if (T + 1 < ntile) {
            if (T + 2 < ntile) { VMCNT(6); } else { VMCNT(0); }
        }
        BAR();
        slot = (slot == 2) ? 0 : slot + 1;
    }

#undef LOAD_AF
#undef LOAD_BF
#undef MFMA_H

#pragma unroll
    for (int f = 0; f < 4; ++f) {
        int row = m0 + wr * 64 + f * 16 + g * 4;
#pragma unroll
        for (int cf = 0; cf < 4; ++cf) {
            int col = n0 + wc * 64 + cf * 16 + l15;
            float bs = bias[col];
            if (col < qcols) bs *= qscale;
#pragma unroll
            for (int r = 0; r < 4; ++r) {
                float v = acc[f][cf][r] + bs;
                C[(size_t)(row + r) * N + col] = (OutT)v;
            }
        }
    }
}

// ---------------------------------------------------------------------------
// Global V transpose: qkvb V block [b,n][h,d] -> VtG[b][h][d][n]  (bf16)
// ---------------------------------------------------------------------------
__global__ __launch_bounds__(256, 1) void vtrans_kernel(
    const bf16* __restrict__ qkv, bf16* __restrict__ vtg)
{
    __shared__ float tile[64][65];
    const int t  = threadIdx.x;
    const int n0 = blockIdx.x * 64;
    const int bh = blockIdx.y;
    const int b  = bh >> 4, h = bh & 15;
    const bf16* src = qkv + (size_t)(b * 2048 + n0) * 3072 + 2048 + h * 64;
#pragma unroll
    for (int r = 0; r < 2; ++r) {
        int s = t + r * 256;
        int row = s >> 3, c8 = (s & 7) * 8;
        union { uint4 v; bf16 h8[8]; } u;
        u.v = *(const uint4*)(src + (size_t)row * 3072 + c8);
#pragma unroll
        for (int j = 0; j < 8; ++j) tile[row][c8 + j] = (float)u.h8[j];
    }
    __syncthreads();
    bf16* dst = vtg + (size_t)bh * (64 * 2048) + n0;
#pragma unroll
    for (int r = 0; r < 2; ++r) {
        int s = t + r * 256;
        int d = s >> 3, n8 = (s & 7) * 8;
        union { uint4 v; bf16 h8[8]; } o;
#pragma unroll
        for (int j = 0; j < 8; ++j) o.h8[j] = (bf16)tile[n8 + j][d];
        *(uint4*)(dst + (size_t)d * 2048 + n8) = o.v;
    }
}

// ---------------------------------------------------------------------------
// Attention v8: v6b algorithm at 4 blocks/CU.
// attn ran 1024 blocks at 3/CU (768 resident) = TWO synchronized rounds
// (2T vs ideal 1.33T).  LDS cut 52224 -> 40960 = exactly 163840/4:
//  - mneg LDS deleted: mask C-init quads loaded per-chunk from global
//    (int4 x4; mask is 8KB, L1-hot, g-group lanes broadcast-coalesce).
//  - Ps stride 88 -> 64 with the SAME XOR block-swizzle as Ks (write
//    ushort4 at block (kt*2+(g>>1))^(l15&7), read b128 at rb0/rb1):
//    conflict-free both sides; logical (q,key) mapping unchanged.
// 1024 blocks = 4/CU x 256 CU = ONE full round.
// ---------------------------------------------------------------------------
__global__ __launch_bounds__(256, 4) void attn_kernel(
    const bf16* __restrict__ qkv, const bf16* __restrict__ vtg,
    const int* __restrict__ mask, bf16* __restrict__ O)
{
    __shared__ __align__(16) bf16 Ks[2][64 * 64];   // 16 KB [key][d]  xor-swz
    __shared__ __align__(16) bf16 Vt[2][64 * 64];   // 16 KB [d][key]  xor-swz
    __shared__ __align__(16) bf16 Ps[4][16 * 64];   //  8 KB per-wave P, xor-swz

    const int t    = threadIdx.x;
    const int lane = t & 63;
    const int wave = t >> 6;
    const int l15  = lane & 15;
    const int g    = lane >> 4;

    const int bid = (blockIdx.x & 7) * 128 + (blockIdx.x >> 3);
    const int qt  = bid & 15;
    const int bh  = bid >> 4;
    const int h   = bh & 15;
    const int b   = bh >> 4;
    const int q0  = qt * 128 + wave * 16;           // tile0; tile1 = q0 + 64

    const int* mrow = mask + b * 2048;

    const size_t RS = 3072;
    const bf16* qp0 = qkv + (size_t)(b * 2048 + q0 + l15) * RS + h * 64 + g * 8;
    const bf16* qp1 = qp0 + (size_t)64 * RS;
    bf16x8 aQ[2][2];
    aQ[0][0] = *(const bf16x8*)(qp0);
    aQ[0][1] = *(const bf16x8*)(qp0 + 32);
    aQ[1][0] = *(const bf16x8*)(qp1);
    aQ[1][1] = *(const bf16x8*)(qp1 + 32);

    const bf16* kbase = qkv + (size_t)(b * 2048) * RS + 1024 + h * 64;
    const bf16* vbase = vtg + (size_t)bh * (64 * 2048);

    const int e0 = t * 8;
    int srow[2], scol[2];
#pragma unroll
    for (int r = 0; r < 2; ++r) {
        int e   = e0 + r * 2048;
        int row = e >> 6;
        int cb  = (e >> 3) & 7;
        srow[r] = row;
        scol[r] = ((cb ^ (row & 7)) * 8);
    }

    const int rb0 = ((g)     ^ (l15 & 7)) * 8;
    const int rb1 = ((4 + g) ^ (l15 & 7)) * 8;
    // swizzled P-store offsets (8B slots), one per kt
    int pw[4];
#pragma unroll
    for (int kt = 0; kt < 4; ++kt)
        pw[kt] = l15 * 64 + (((kt * 2 + (g >> 1)) ^ (l15 & 7)) * 8) + (g & 1) * 4;

    const f32x4 z = {0.f, 0.f, 0.f, 0.f};
    f32x4 o0[4] = {z, z, z, z}, o1[4] = {z, z, z, z};
    f32x4 lacc0 = z, lacc1 = z;

    bf16x8 ones;
#pragma unroll
    for (int j = 0; j < 8; ++j) ones[j] = (bf16)1.0f;

#pragma unroll
    for (int r = 0; r < 2; ++r) {
        GLOAD_LDS(kbase + (size_t)srow[r] * RS + scol[r],   &Ks[0][e0 + r * 2048]);
        GLOAD_LDS(vbase + (size_t)srow[r] * 2048 + scol[r], &Vt[0][e0 + r * 2048]);
    }
    asm volatile("s_waitcnt vmcnt(0)" ::: "memory");
    __syncthreads();

    for (int i = 0; i < 32; ++i) {
        const int kc  = i * 64;
        const int buf = i & 1;

        if (i + 1 < 32) {
#pragma unroll
            for (int r = 0; r < 2; ++r) {
                GLOAD_LDS(kbase + (size_t)(kc + 64 + srow[r]) * RS + scol[r],
                          &Ks[buf ^ 1][e0 + r * 2048]);
                GLOAD_LDS(vbase + (size_t)srow[r] * 2048 + kc + 64 + scol[r],
                          &Vt[buf ^ 1][e0 + r * 2048]);
            }
        }

        // ---- mask quads from global (L1-hot): key = kc+kt*16+g*4+r ----
        f32x4 mb4[4];
#pragma unroll
        for (int kt = 0; kt < 4; ++kt) {
            int4 mi = *(const int4*)(mrow + kc + kt * 16 + g * 4);
            mb4[kt][0] = mi.x ? 0.0f : -1e30f;
            mb4[kt][1] = mi.y ? 0.0f : -1e30f;
            mb4[kt][2] = mi.z ? 0.0f : -1e30f;
            mb4[kt][3] = mi.w ? 0.0f : -1e30f;
        }

        // ---- K fragments, shared by both q-tiles ----
        bf16x8 bk[4][2];
#pragma unroll
        for (int kt = 0; kt < 4; ++kt) {
            const bf16* kr = &Ks[buf][(kt * 16 + l15) * 64];
            bk[kt][0] = *(const bf16x8*)(kr + rb0);
            bk[kt][1] = *(const bf16x8*)(kr + rb1);
        }

        // ---- tile 0: S^T = mfma(K, Q) (mask in C-init), packed P store ----
        f32x4 S[4];
#pragma unroll
        for (int kt = 0; kt < 4; ++kt) {
            S[kt] = MFMA16(bk[kt][0], aQ[0][0], mb4[kt]);
            S[kt] = MFMA16(bk[kt][1], aQ[0][1], S[kt]);
        }
#pragma unroll
        for (int kt = 0; kt < 4; ++kt) {
            union { bf16 hh[4]; ushort4 u; } pk;
#pragma unroll
            for (int r = 0; r < 4; ++r)
                pk.hh[r] = (bf16)__builtin_amdgcn_exp2f(S[kt][r]);
            *(ushort4*)(&Ps[wave][pw[kt]]) = pk.u;
        }
        asm volatile("s_waitcnt lgkmcnt(0)" ::: "memory");
        __builtin_amdgcn_sched_barrier(0);
        const bf16x8 aP00 = *(const bf16x8*)(&Ps[wave][l15 * 64 + rb0]);
        const bf16x8 aP01 = *(const bf16x8*)(&Ps[wave][l15 * 64 + rb1]);
        asm volatile("s_waitcnt lgkmcnt(0)" ::: "memory");  // aP0 in regs
        __builtin_amdgcn_sched_barrier(0);

        // ---- tile 1: S^T (reusing bk) ----
#pragma unroll
        for (int kt = 0; kt < 4; ++kt) {
            S[kt] = MFMA16(bk[kt][0], aQ[1][0], mb4[kt]);
            S[kt] = MFMA16(bk[kt][1], aQ[1][1], S[kt]);
        }

        // ---- V fragments, read ONCE, shared by both q-tiles ----
        bf16x8 bv[4][2];
#pragma unroll
        for (int dt = 0; dt < 4; ++dt) {
            const bf16* vr = &Vt[buf][(dt * 16 + l15) * 64];
            bv[dt][0] = *(const bf16x8*)(vr + rb0);
            bv[dt][1] = *(const bf16x8*)(vr + rb1);
        }

#pragma unroll
        for (int kt = 0; kt < 4; ++kt) {
            union { bf16 hh[4]; ushort4 u; } pk;
#pragma unroll
            for (int r = 0; r < 4; ++r)
                pk.hh[r] = (bf16)__builtin_amdgcn_exp2f(S[kt][r]);
            *(ushort4*)(&Ps[wave][pw[kt]]) = pk.u;
        }

        // ---- tile 0 accumulate (overlaps tile-1 P roundtrip) ----
        lacc0 = MFMA16(aP00, ones, lacc0);
        lacc0 = MFMA16(aP01, ones, lacc0);
#pragma unroll
        for (int dt = 0; dt < 4; ++dt) {
            o0[dt] = MFMA16(aP00, bv[dt][0], o0[dt]);
            o0[dt] = MFMA16(aP01, bv[dt][1], o0[dt]);
        }
        asm volatile("s_waitcnt lgkmcnt(0)" ::: "memory");  // P1 committed
        __builtin_amdgcn_sched_barrier(0);
        const bf16x8 aP10 = *(const bf16x8*)(&Ps[wave][l15 * 64 + rb0]);
        const bf16x8 aP11 = *(const bf16x8*)(&Ps[wave][l15 * 64 + rb1]);

        // ---- tile 1 accumulate ----
        lacc1 = MFMA16(aP10, ones, lacc1);
        lacc1 = MFMA16(aP11, ones, lacc1);
#pragma unroll
        for (int dt = 0; dt < 4; ++dt) {
            o1[dt] = MFMA16(aP10, bv[dt][0], o1[dt]);
            o1[dt] = MFMA16(aP11, bv[dt][1], o1[dt]);
        }

        asm volatile("s_waitcnt vmcnt(0)" ::: "memory");  // prefetch landed
        __syncthreads();   // single barrier: buf^1 published, buf reads done
    }

    float inv0[4], inv1[4];
#pragma unroll
    for (int r = 0; r < 4; ++r) {
        inv0[r] = 1.0f / fmaxf(lacc0[r], 1e-30f);
        inv1[r] = 1.0f / fmaxf(lacc1[r], 1e-30f);
    }
#pragma unroll
    for (int nt = 0; nt < 4; ++nt) {
#pragma unroll
        for (int r = 0; r < 4; ++r) {
            int d = nt * 16 + l15;
            int row0 = q0 + g * 4 + r;
            O[(size_t)(b * 2048 + row0) * 1024 + h * 64 + d] = (bf16)(o0[nt][r] * inv0[r]);
            O[(size_t)(b * 2048 + row0 + 64) * 1024 + h * 64 + d] = (bf16)(o1[nt][r] * inv1[r]);
        }
    }
}

// ---------------------------------------------------------------------------
extern "C" void kernel_launch(void* const* d_in, const int* in_sizes, int n_in,
                              void* d_out, int out_size, void* d_ws, size_t ws_size,
                              hipStream_t stream)
{
    const float* x     = (const float*)d_in[0];
    const int*   mask  = (const int*)d_in[1];
    const float* w_qkv = (const float*)d_in[2];
    const float* b_qkv = (const float*)d_in[3];
    const float* w_out = (const float*)d_in[4];
    const float* b_out = (const float*)d_in[5];
    float* out = (float*)d_out;

    char* ws = (char*)d_ws;
    bf16* qkvb  = (bf16*)(ws);                 // 48 MiB: [8192][3072]
    bf16* Obuf  = (bf16*)(ws + 50331648);      // 16 MiB: [8192][1024]
    bf16* xb    = (bf16*)(ws + 67108864);      // 16 MiB: [8192][1024]
    bf16* wqkvT = (bf16*)(ws + 83886080);      //  6 MiB: [3072][1024]
    bf16* woutT = (bf16*)(ws + 90177536);      //  2 MiB: [1024][1024]
    // VtG aliases xb: xb's last reader is the qkv GEMM, vtrans runs after it.
    bf16* vtg   = xb;                          // 16 MiB: [64 bh][64 d][2048 n]

    prep_kernel<<<dim3(9216), 256, 0, stream>>>(x, xb, w_qkv, wqkvT, w_out, woutT);
    gemm128x256_kernel<bf16><<<dim3(768), 512, 0, stream>>>(
        xb, wqkvT, b_qkv, qkvb, 8192, 3072, 1024, 1024, QSCALE, 12);
    vtrans_kernel<<<dim3(32, 64), 256, 0, stream>>>(qkvb, vtg);
    attn_kernel<<<dim3(1024), 256, 0, stream>>>(qkvb, vtg, mask, Obuf);
    gemm128x256_kernel<float><<<dim3(256), 512, 0, stream>>>(
        Obuf, woutT, b_out, out, 8192, 1024, 1024, 0, 1.0f, 4);
}

// Round 14
// 286.297 us; speedup vs baseline: 1.3678x; 1.3678x over previous
//
#include <hip/hip_runtime.h>

// ---------------------------------------------------------------------------
// AttentionMulti: x[4,2048,1024] fp32 -> qkv -> 16-head attention (D=64,
// scale=0.5, key-mask) -> out proj.  Inputs/outputs fp32, mask int32.
// Internal compute in bf16 MFMA.
// ---------------------------------------------------------------------------

typedef __bf16 bf16;
typedef __attribute__((ext_vector_type(8))) __bf16 bf16x8;
typedef __attribute__((ext_vector_type(4))) float f32x4;

#define MFMA16(a, b, c) __builtin_amdgcn_mfma_f32_16x16x32_bf16(a, b, c, 0, 0, 0)
#define GLOAD_LDS(src, dst) __builtin_amdgcn_global_load_lds( \
    (const __attribute__((address_space(1))) void*)(src),     \
    (__attribute__((address_space(3))) void*)(dst), 16, 0, 0)
#define BAR() __builtin_amdgcn_s_barrier()
#define VMCNT(n) asm volatile("s_waitcnt vmcnt(" #n ")" ::: "memory")

// 0.5 * log2(e): folded into Q (w_qkv cols 0..1023 and b_qkv[0..1023])
#define QSCALE 0.72134752f

// ---------------------------------------------------------------------------
// Fused prologue: cvt x->bf16 (blocks 0..8191) || transpose w_qkv
// (blocks 8192..8959) || transpose w_out (blocks 8960..9215).
// ---------------------------------------------------------------------------
__device__ __forceinline__ void transpose_tile(
    const float* __restrict__ in, bf16* __restrict__ out, int R, int C,
    int scale_rows, float scale, int bx, int by, int t, float (*s)[65])
{
    const int r0 = by * 64;
    const int c0 = bx * 64;
    const int tr  = t >> 4;
    const int tc4 = (t & 15) * 4;
#pragma unroll
    for (int p = 0; p < 4; ++p) {
        int r = tr + p * 16;
        float4 v = *(const float4*)(in + (size_t)(r0 + r) * C + c0 + tc4);
        s[r][tc4 + 0] = v.x; s[r][tc4 + 1] = v.y;
        s[r][tc4 + 2] = v.z; s[r][tc4 + 3] = v.w;
    }
    __syncthreads();
    const int cw  = t >> 3;
    const int rw8 = (t & 7) * 8;
#pragma unroll
    for (int p = 0; p < 2; ++p) {
        int c = cw + p * 32;
        float f = (c0 + c) < scale_rows ? scale : 1.0f;
        union { uint4 v; bf16 h[8]; } u;
#pragma unroll
        for (int j = 0; j < 8; ++j) u.h[j] = (bf16)(s[rw8 + j][c] * f);
        *(uint4*)(out + (size_t)(c0 + c) * R + r0 + rw8) = u.v;
    }
}

__global__ __launch_bounds__(256, 1) void prep_kernel(
    const float* __restrict__ x, bf16* __restrict__ xb,
    const float* __restrict__ w_qkv, bf16* __restrict__ wqkvT,
    const float* __restrict__ w_out, bf16* __restrict__ woutT)
{
    __shared__ float s[64][65];
    const int t = threadIdx.x;
    int blk = blockIdx.x;
    if (blk < 8192) {
        int i = blk * 256 + t;
        float4 v = *(const float4*)(x + (size_t)i * 4);
        union { ushort4 u; bf16 h[4]; } o;
        o.h[0] = (bf16)v.x; o.h[1] = (bf16)v.y;
        o.h[2] = (bf16)v.z; o.h[3] = (bf16)v.w;
        *(ushort4*)(xb + (size_t)i * 4) = o.u;
        return;
    }
    blk -= 8192;
    if (blk < 768) {
        transpose_tile(w_qkv, wqkvT, 1024, 3072, 1024, QSCALE,
                       blk % 48, blk / 48, t, s);
    } else {
        blk -= 768;
        transpose_tile(w_out, woutT, 1024, 1024, 0, 1.0f,
                       blk % 16, blk / 16, t, s);
    }
}

// ---------------------------------------------------------------------------
// 128x256-tile GEMM, BK=64, 3-slot, 2 phases/K-tile (round-10 known-good;
// GEMM matrix fully explored -> plateau ~440 TF, see r11/r12 notes).
// ---------------------------------------------------------------------------
template <typename OutT>
__global__ __launch_bounds__(512, 2) void gemm128x256_kernel(
    const bf16* __restrict__ A, const bf16* __restrict__ Bt,
    const float* __restrict__ bias, OutT* __restrict__ C,
    int M, int N, int K, int qcols, float qscale, int nbx)
{
    __shared__ __align__(16) bf16 As[3 * 128 * 64];   // 48 KiB
    __shared__ __align__(16) bf16 Bs[3 * 256 * 64];   // 96 KiB

    const int t    = threadIdx.x;
    const int lane = t & 63;
    const int wave = t >> 6;
    const int wr   = wave >> 2;
    const int wc   = wave & 3;
    const int l15  = lane & 15;
    const int g    = lane >> 4;

    const int nwg  = gridDim.x;
    const int per  = nwg >> 3;
    const int mper = per / nbx;
    const int wg   = blockIdx.x;
    const int xcd  = wg & 7;
    const int idx  = wg >> 3;
    const int m0   = (xcd * mper + idx % mper) * 128;
    const int n0   = (idx / mper) * 256;

    const int ntile = K >> 6;

    int srow[2], sblk[2];
#pragma unroll
    for (int r = 0; r < 2; ++r) {
        int s = t * 16 + r * 8192;
        srow[r] = s >> 7;
        int blk = (s >> 4) & 7;
        sblk[r] = blk ^ (srow[r] & 7);
    }
    const int ldst0 = t * 8;

    const bf16* Abase = A  + (size_t)m0 * K;
    const bf16* Bbase = Bt + (size_t)n0 * K;

    const f32x4 z = {0.f, 0.f, 0.f, 0.f};
    f32x4 acc[4][4];
#pragma unroll
    for (int i = 0; i < 4; ++i)
#pragma unroll
        for (int j = 0; j < 4; ++j) acc[i][j] = z;

    auto stageA = [&](int tile, int slot) {
        if (tile >= ntile) return;
        bf16* dst = As + slot * 8192;
        const bf16* src = Abase + tile * 64;
#pragma unroll
        for (int r = 0; r < 2; ++r)
            GLOAD_LDS(src + (size_t)srow[r] * K + sblk[r] * 8,
                      dst + ldst0 + r * 4096);
    };
    auto stageBh = [&](int tile, int slot, int h) {
        if (tile >= ntile) return;
        bf16* dst = Bs + slot * 16384 + h * 8192;
        const bf16* src = Bbase + (size_t)(h * 128) * K + tile * 64;
#pragma unroll
        for (int r = 0; r < 2; ++r)
            GLOAD_LDS(src + (size_t)srow[r] * K + sblk[r] * 8,
                      dst + ldst0 + r * 4096);
    };

#define LOAD_AF(slot)                                                         \
    _Pragma("unroll")                                                         \
    for (int f = 0; f < 4; ++f) {                                             \
        int row = wr * 64 + f * 16 + l15;                                     \
        _Pragma("unroll")                                                     \
        for (int ks = 0; ks < 2; ++ks)                                        \
            af[f][ks] = *(const bf16x8*)(&As[(slot) * 8192 + row * 64 +       \
                            (((ks * 4 + g) ^ (row & 7)) * 8)]);               \
    }
#define LOAD_BF(slot, half, dstv)                                             \
    _Pragma("unroll")                                                         \
    for (int c2 = 0; c2 < 2; ++c2) {                                          \
        int row = wc * 64 + ((half) * 2 + c2) * 16 + l15;                     \
        _Pragma("unroll")                                                     \
        for (int ks = 0; ks < 2; ++ks)                                        \
            dstv[c2][ks] = *(const bf16x8*)(&Bs[(slot) * 16384 + row * 64 +   \
                            (((ks * 4 + g) ^ (row & 7)) * 8)]);               \
    }
#define MFMA_H(bv, half)                                                      \
    {                                                                         \
        __builtin_amdgcn_s_setprio(1);                                        \
        _Pragma("unroll")                                                     \
        for (int f = 0; f < 4; ++f)                                           \
            _Pragma("unroll")                                                 \
            for (int c2 = 0; c2 < 2; ++c2) {                                  \
                acc[f][(half) * 2 + c2] = MFMA16(                             \
                    af[f][0], bv[c2][0], acc[f][(half) * 2 + c2]);            \
                acc[f][(half) * 2 + c2] = MFMA16(                             \
                    af[f][1], bv[c2][1], acc[f][(half) * 2 + c2]);            \
            }                                                                 \
        __builtin_amdgcn_s_setprio(0);                                        \
    }

    stageA(0, 0); stageBh(0, 0, 0); stageBh(0, 0, 1);
    stageA(1, 1); stageBh(1, 1, 0); stageBh(1, 1, 1);
    VMCNT(6);
    BAR();

    int slot = 0;
    for (int T = 0; T < ntile; ++T) {
        int slot2 = slot + 2; if (slot2 >= 3) slot2 -= 3;
        bf16x8 af[4][2], blo[2][2], bhi[2][2];
        LOAD_AF(slot);
        LOAD_BF(slot, 0, blo);
        stageA(T + 2, slot2);
        stageBh(T + 2, slot2, 0);
        MFMA_H(blo, 0);
        BAR();
        LOAD_BF(slot, 1, bhi);
        stageBh(T + 2, slot2, 1);
        MFMA_H(bhi, 1);
        if (T + 1 < ntile) {
            if (T + 2 < ntile) { VMCNT(6); } else { VMCNT(0); }
        }
        BAR();
        slot = (slot == 2) ? 0 : slot + 1;
    }

#undef LOAD_AF
#undef LOAD_BF
#undef MFMA_H

#pragma unroll
    for (int f = 0; f < 4; ++f) {
        int row = m0 + wr * 64 + f * 16 + g * 4;
#pragma unroll
        for (int cf = 0; cf < 4; ++cf) {
            int col = n0 + wc * 64 + cf * 16 + l15;
            float bs = bias[col];
            if (col < qcols) bs *= qscale;
#pragma unroll
            for (int r = 0; r < 4; ++r) {
                float v = acc[f][cf][r] + bs;
                C[(size_t)(row + r) * N + col] = (OutT)v;
            }
        }
    }
}

// ---------------------------------------------------------------------------
// Global V transpose: qkvb V block [b,n][h,d] -> VtG[b][h][d][n]  (bf16)
// ---------------------------------------------------------------------------
__global__ __launch_bounds__(256, 1) void vtrans_kernel(
    const bf16* __restrict__ qkv, bf16* __restrict__ vtg)
{
    __shared__ float tile[64][65];
    const int t  = threadIdx.x;
    const int n0 = blockIdx.x * 64;
    const int bh = blockIdx.y;
    const int b  = bh >> 4, h = bh & 15;
    const bf16* src = qkv + (size_t)(b * 2048 + n0) * 3072 + 2048 + h * 64;
#pragma unroll
    for (int r = 0; r < 2; ++r) {
        int s = t + r * 256;
        int row = s >> 3, c8 = (s & 7) * 8;
        union { uint4 v; bf16 h8[8]; } u;
        u.v = *(const uint4*)(src + (size_t)row * 3072 + c8);
#pragma unroll
        for (int j = 0; j < 8; ++j) tile[row][c8 + j] = (float)u.h8[j];
    }
    __syncthreads();
    bf16* dst = vtg + (size_t)bh * (64 * 2048) + n0;
#pragma unroll
    for (int r = 0; r < 2; ++r) {
        int s = t + r * 256;
        int d = s >> 3, n8 = (s & 7) * 8;
        union { uint4 v; bf16 h8[8]; } o;
#pragma unroll
        for (int j = 0; j < 8; ++j) o.h8[j] = (bf16)tile[n8 + j][d];
        *(uint4*)(dst + (size_t)d * 2048 + n8) = o.v;
    }
}

// ---------------------------------------------------------------------------
// Attention v8b: v8's 40960-B LDS diet (mask-from-global + Ps stride-64
// swizzle) with launch_bounds REVERTED to (256,3).
// Round-13 lesson: (256,4) clamped the allocator to 64 VGPR (needs ~76) ->
// 500 MB scratch spill traffic, attn 99 -> 220-313 us.  launch_bounds only
// constrains regalloc; residency comes from resources.  At VGPR ~76 the
// LDS (40960 = 163840/4 exactly) is the binding limit -> 4 blocks/CU,
// 1024 blocks = ONE full round (was 2 rounds at 3/CU).
// ---------------------------------------------------------------------------
__global__ __launch_bounds__(256, 3) void attn_kernel(
    const bf16* __restrict__ qkv, const bf16* __restrict__ vtg,
    const int* __restrict__ mask, bf16* __restrict__ O)
{
    __shared__ __align__(16) bf16 Ks[2][64 * 64];   // 16 KB [key][d]  xor-swz
    __shared__ __align__(16) bf16 Vt[2][64 * 64];   // 16 KB [d][key]  xor-swz
    __shared__ __align__(16) bf16 Ps[4][16 * 64];   //  8 KB per-wave P, xor-swz

    const int t    = threadIdx.x;
    const int lane = t & 63;
    const int wave = t >> 6;
    const int l15  = lane & 15;
    const int g    = lane >> 4;

    const int bid = (blockIdx.x & 7) * 128 + (blockIdx.x >> 3);
    const int qt  = bid & 15;
    const int bh  = bid >> 4;
    const int h   = bh & 15;
    const int b   = bh >> 4;
    const int q0  = qt * 128 + wave * 16;           // tile0; tile1 = q0 + 64

    const int* mrow = mask + b * 2048;

    const size_t RS = 3072;
    const bf16* qp0 = qkv + (size_t)(b * 2048 + q0 + l15) * RS + h * 64 + g * 8;
    const bf16* qp1 = qp0 + (size_t)64 * RS;
    bf16x8 aQ[2][2];
    aQ[0][0] = *(const bf16x8*)(qp0);
    aQ[0][1] = *(const bf16x8*)(qp0 + 32);
    aQ[1][0] = *(const bf16x8*)(qp1);
    aQ[1][1] = *(const bf16x8*)(qp1 + 32);

    const bf16* kbase = qkv + (size_t)(b * 2048) * RS + 1024 + h * 64;
    const bf16* vbase = vtg + (size_t)bh * (64 * 2048);

    const int e0 = t * 8;
    int srow[2], scol[2];
#pragma unroll
    for (int r = 0; r < 2; ++r) {
        int e   = e0 + r * 2048;
        int row = e >> 6;
        int cb  = (e >> 3) & 7;
        srow[r] = row;
        scol[r] = ((cb ^ (row & 7)) * 8);
    }

    const int rb0 = ((g)     ^ (l15 & 7)) * 8;
    const int rb1 = ((4 + g) ^ (l15 & 7)) * 8;
    // swizzled P-store offsets (8B slots), one per kt
    int pw[4];
#pragma unroll
    for (int kt = 0; kt < 4; ++kt)
        pw[kt] = l15 * 64 + (((kt * 2 + (g >> 1)) ^ (l15 & 7)) * 8) + (g & 1) * 4;

    const f32x4 z = {0.f, 0.f, 0.f, 0.f};
    f32x4 o0[4] = {z, z, z, z}, o1[4] = {z, z, z, z};
    f32x4 lacc0 = z, lacc1 = z;

    bf16x8 ones;
#pragma unroll
    for (int j = 0; j < 8; ++j) ones[j] = (bf16)1.0f;

#pragma unroll
    for (int r = 0; r < 2; ++r) {
        GLOAD_LDS(kbase + (size_t)srow[r] * RS + scol[r],   &Ks[0][e0 + r * 2048]);
        GLOAD_LDS(vbase + (size_t)srow[r] * 2048 + scol[r], &Vt[0][e0 + r * 2048]);
    }
    asm volatile("s_waitcnt vmcnt(0)" ::: "memory");
    __syncthreads();

    for (int i = 0; i < 32; ++i) {
        const int kc  = i * 64;
        const int buf = i & 1;

        if (i + 1 < 32) {
#pragma unroll
            for (int r = 0; r < 2; ++r) {
                GLOAD_LDS(kbase + (size_t)(kc + 64 + srow[r]) * RS + scol[r],
                          &Ks[buf ^ 1][e0 + r * 2048]);
                GLOAD_LDS(vbase + (size_t)srow[r] * 2048 + kc + 64 + scol[r],
                          &Vt[buf ^ 1][e0 + r * 2048]);
            }
        }

        // ---- mask quads from global (L1-hot): key = kc+kt*16+g*4+r ----
        f32x4 mb4[4];
#pragma unroll
        for (int kt = 0; kt < 4; ++kt) {
            int4 mi = *(const int4*)(mrow + kc + kt * 16 + g * 4);
            mb4[kt][0] = mi.x ? 0.0f : -1e30f;
            mb4[kt][1] = mi.y ? 0.0f : -1e30f;
            mb4[kt][2] = mi.z ? 0.0f : -1e30f;
            mb4[kt][3] = mi.w ? 0.0f : -1e30f;
        }

        // ---- K fragments, shared by both q-tiles ----
        bf16x8 bk[4][2];
#pragma unroll
        for (int kt = 0; kt < 4; ++kt) {
            const bf16* kr = &Ks[buf][(kt * 16 + l15) * 64];
            bk[kt][0] = *(const bf16x8*)(kr + rb0);
            bk[kt][1] = *(const bf16x8*)(kr + rb1);
        }

        // ---- tile 0: S^T = mfma(K, Q) (mask in C-init), packed P store ----
        f32x4 S[4];
#pragma unroll
        for (int kt = 0; kt < 4; ++kt) {
            S[kt] = MFMA16(bk[kt][0], aQ[0][0], mb4[kt]);
            S[kt] = MFMA16(bk[kt][1], aQ[0][1], S[kt]);
        }
#pragma unroll
        for (int kt = 0; kt < 4; ++kt) {
            union { bf16 hh[4]; ushort4 u; } pk;
#pragma unroll
            for (int r = 0; r < 4; ++r)
                pk.hh[r] = (bf16)__builtin_amdgcn_exp2f(S[kt][r]);
            *(ushort4*)(&Ps[wave][pw[kt]]) = pk.u;
        }
        asm volatile("s_waitcnt lgkmcnt(0)" ::: "memory");
        __builtin_amdgcn_sched_barrier(0);
        const bf16x8 aP00 = *(const bf16x8*)(&Ps[wave][l15 * 64 + rb0]);
        const bf16x8 aP01 = *(const bf16x8*)(&Ps[wave][l15 * 64 + rb1]);
        asm volatile("s_waitcnt lgkmcnt(0)" ::: "memory");  // aP0 in regs
        __builtin_amdgcn_sched_barrier(0);

        // ---- tile 1: S^T (reusing bk) ----
#pragma unroll
        for (int kt = 0; kt < 4; ++kt) {
            S[kt] = MFMA16(bk[kt][0], aQ[1][0], mb4[kt]);
            S[kt] = MFMA16(bk[kt][1], aQ[1][1], S[kt]);
        }

        // ---- V fragments, read ONCE, shared by both q-tiles ----
        bf16x8 bv[4][2];
#pragma unroll
        for (int dt = 0; dt < 4; ++dt) {
            const bf16* vr = &Vt[buf][(dt * 16 + l15) * 64];
            bv[dt][0] = *(const bf16x8*)(vr + rb0);
            bv[dt][1] = *(const bf16x8*)(vr + rb1);
        }

#pragma unroll
        for (int kt = 0; kt < 4; ++kt) {
            union { bf16 hh[4]; ushort4 u; } pk;
#pragma unroll
            for (int r = 0; r < 4; ++r)
                pk.hh[r] = (bf16)__builtin_amdgcn_exp2f(S[kt][r]);
            *(ushort4*)(&Ps[wave][pw[kt]]) = pk.u;
        }

        // ---- tile 0 accumulate (overlaps tile-1 P roundtrip) ----
        lacc0 = MFMA16(aP00, ones, lacc0);
        lacc0 = MFMA16(aP01, ones, lacc0);
#pragma unroll
        for (int dt = 0; dt < 4; ++dt) {
            o0[dt] = MFMA16(aP00, bv[dt][0], o0[dt]);
            o0[dt] = MFMA16(aP01, bv[dt][1], o0[dt]);
        }
        asm volatile("s_waitcnt lgkmcnt(0)" ::: "memory");  // P1 committed
        __builtin_amdgcn_sched_barrier(0);
        const bf16x8 aP10 = *(const bf16x8*)(&Ps[wave][l15 * 64 + rb0]);
        const bf16x8 aP11 = *(const bf16x8*)(&Ps[wave][l15 * 64 + rb1]);

        // ---- tile 1 accumulate ----
        lacc1 = MFMA16(aP10, ones, lacc1);
        lacc1 = MFMA16(aP11, ones, lacc1);
#pragma unroll
        for (int dt = 0; dt < 4; ++dt) {
            o1[dt] = MFMA16(aP10, bv[dt][0], o1[dt]);
            o1[dt] = MFMA16(aP11, bv[dt][1], o1[dt]);
        }

        asm volatile("s_waitcnt vmcnt(0)" ::: "memory");  // prefetch landed
        __syncthreads();   // single barrier: buf^1 published, buf reads done
    }

    float inv0[4], inv1[4];
#pragma unroll
    for (int r = 0; r < 4; ++r) {
        inv0[r] = 1.0f / fmaxf(lacc0[r], 1e-30f);
        inv1[r] = 1.0f / fmaxf(lacc1[r], 1e-30f);
    }
#pragma unroll
    for (int nt = 0; nt < 4; ++nt) {
#pragma unroll
        for (int r = 0; r < 4; ++r) {
            int d = nt * 16 + l15;
            int row0 = q0 + g * 4 + r;
            O[(size_t)(b * 2048 + row0) * 1024 + h * 64 + d] = (bf16)(o0[nt][r] * inv0[r]);
            O[(size_t)(b * 2048 + row0 + 64) * 1024 + h * 64 + d] = (bf16)(o1[nt][r] * inv1[r]);
        }
    }
}

// ---------------------------------------------------------------------------
extern "C" void kernel_launch(void* const* d_in, const int* in_sizes, int n_in,
                              void* d_out, int out_size, void* d_ws, size_t ws_size,
                              hipStream_t stream)
{
    const float* x     = (const float*)d_in[0];
    const int*   mask  = (const int*)d_in[1];
    const float* w_qkv = (const float*)d_in[2];
    const float* b_qkv = (const float*)d_in[3];
    const float* w_out = (const float*)d_in[4];
    const float* b_out = (const float*)d_in[5];
    float* out = (float*)d_out;

    char* ws = (char*)d_ws;
    bf16* qkvb  = (bf16*)(ws);                 // 48 MiB: [8192][3072]
    bf16* Obuf  = (bf16*)(ws + 50331648);      // 16 MiB: [8192][1024]
    bf16* xb    = (bf16*)(ws + 67108864);      // 16 MiB: [8192][1024]
    bf16* wqkvT = (bf16*)(ws + 83886080);      //  6 MiB: [3072][1024]
    bf16* woutT = (bf16*)(ws + 90177536);      //  2 MiB: [1024][1024]
    // VtG aliases xb: xb's last reader is the qkv GEMM, vtrans runs after it.
    bf16* vtg   = xb;                          // 16 MiB: [64 bh][64 d][2048 n]

    prep_kernel<<<dim3(9216), 256, 0, stream>>>(x, xb, w_qkv, wqkvT, w_out, woutT);
    gemm128x256_kernel<bf16><<<dim3(768), 512, 0, stream>>>(
        xb, wqkvT, b_qkv, qkvb, 8192, 3072, 1024, 1024, QSCALE, 12);
    vtrans_kernel<<<dim3(32, 64), 256, 0, stream>>>(qkvb, vtg);
    attn_kernel<<<dim3(1024), 256, 0, stream>>>(qkvb, vtg, mask, Obuf);
    gemm128x256_kernel<float><<<dim3(256), 512, 0, stream>>>(
        Obuf, woutT, b_out, out, 8192, 1024, 1024, 0, 1.0f, 4);
}

// Round 15
// 274.815 us; speedup vs baseline: 1.4250x; 1.0418x over previous
//
#include <hip/hip_runtime.h>

// ---------------------------------------------------------------------------
// AttentionMulti: x[4,2048,1024] fp32 -> qkv -> 16-head attention (D=64,
// scale=0.5, key-mask) -> out proj.  Inputs/outputs fp32, mask int32.
// Internal compute in bf16 MFMA.
// Round-15: gemm1 epilogue writes V DIRECTLY TRANSPOSED into vtg (vtrans
// kernel deleted); qkvb shrunk to [8192][2048] (Q+K only, ldc=2048).
// attn restored to v6b (r10 known-good 99us; r13/r14 4-blocks/CU attempts
// both failed -- LDS granule/reservation leaves 3 slots at 40960B).
// ---------------------------------------------------------------------------

typedef __bf16 bf16;
typedef __attribute__((ext_vector_type(8))) __bf16 bf16x8;
typedef __attribute__((ext_vector_type(4))) float f32x4;

#define MFMA16(a, b, c) __builtin_amdgcn_mfma_f32_16x16x32_bf16(a, b, c, 0, 0, 0)
#define GLOAD_LDS(src, dst) __builtin_amdgcn_global_load_lds( \
    (const __attribute__((address_space(1))) void*)(src),     \
    (__attribute__((address_space(3))) void*)(dst), 16, 0, 0)
#define BAR() __builtin_amdgcn_s_barrier()
#define VMCNT(n) asm volatile("s_waitcnt vmcnt(" #n ")" ::: "memory")

// 0.5 * log2(e): folded into Q (w_qkv cols 0..1023 and b_qkv[0..1023])
#define QSCALE 0.72134752f

// ---------------------------------------------------------------------------
// Fused prologue: cvt x->bf16 (blocks 0..8191) || transpose w_qkv
// (blocks 8192..8959) || transpose w_out (blocks 8960..9215).
// ---------------------------------------------------------------------------
__device__ __forceinline__ void transpose_tile(
    const float* __restrict__ in, bf16* __restrict__ out, int R, int C,
    int scale_rows, float scale, int bx, int by, int t, float (*s)[65])
{
    const int r0 = by * 64;
    const int c0 = bx * 64;
    const int tr  = t >> 4;
    const int tc4 = (t & 15) * 4;
#pragma unroll
    for (int p = 0; p < 4; ++p) {
        int r = tr + p * 16;
        float4 v = *(const float4*)(in + (size_t)(r0 + r) * C + c0 + tc4);
        s[r][tc4 + 0] = v.x; s[r][tc4 + 1] = v.y;
        s[r][tc4 + 2] = v.z; s[r][tc4 + 3] = v.w;
    }
    __syncthreads();
    const int cw  = t >> 3;
    const int rw8 = (t & 7) * 8;
#pragma unroll
    for (int p = 0; p < 2; ++p) {
        int c = cw + p * 32;
        float f = (c0 + c) < scale_rows ? scale : 1.0f;
        union { uint4 v; bf16 h[8]; } u;
#pragma unroll
        for (int j = 0; j < 8; ++j) u.h[j] = (bf16)(s[rw8 + j][c] * f);
        *(uint4*)(out + (size_t)(c0 + c) * R + r0 + rw8) = u.v;
    }
}

__global__ __launch_bounds__(256, 1) void prep_kernel(
    const float* __restrict__ x, bf16* __restrict__ xb,
    const float* __restrict__ w_qkv, bf16* __restrict__ wqkvT,
    const float* __restrict__ w_out, bf16* __restrict__ woutT)
{
    __shared__ float s[64][65];
    const int t = threadIdx.x;
    int blk = blockIdx.x;
    if (blk < 8192) {
        int i = blk * 256 + t;
        float4 v = *(const float4*)(x + (size_t)i * 4);
        union { ushort4 u; bf16 h[4]; } o;
        o.h[0] = (bf16)v.x; o.h[1] = (bf16)v.y;
        o.h[2] = (bf16)v.z; o.h[3] = (bf16)v.w;
        *(ushort4*)(xb + (size_t)i * 4) = o.u;
        return;
    }
    blk -= 8192;
    if (blk < 768) {
        transpose_tile(w_qkv, wqkvT, 1024, 3072, 1024, QSCALE,
                       blk % 48, blk / 48, t, s);
    } else {
        blk -= 768;
        transpose_tile(w_out, woutT, 1024, 1024, 0, 1.0f,
                       blk % 16, blk / 16, t, s);
    }
}

// ---------------------------------------------------------------------------
// 128x256-tile GEMM, BK=64, 3-slot, 2 phases/K-tile (round-10 known-good).
// NEW: optional V-transposed epilogue.  If vtg != nullptr and this block's
// n0 >= 2048 (V columns of the qkv projection), the tile is stored as
// vtg[b*16+h][d][n] (n = token row) instead of C.  Each lane's 4 acc
// values (4 consecutive rows, one col) = 4 consecutive n -> one aligned
// ushort4 store.  C rows use ldc (qkvb is [8192][2048], Q+K only).
// ---------------------------------------------------------------------------
template <typename OutT>
__global__ __launch_bounds__(512, 2) void gemm128x256_kernel(
    const bf16* __restrict__ A, const bf16* __restrict__ Bt,
    const float* __restrict__ bias, OutT* __restrict__ C,
    int M, int ldc, int K, int qcols, float qscale, int nbx,
    bf16* __restrict__ vtg)
{
    __shared__ __align__(16) bf16 As[3 * 128 * 64];   // 48 KiB
    __shared__ __align__(16) bf16 Bs[3 * 256 * 64];   // 96 KiB

    const int t    = threadIdx.x;
    const int lane = t & 63;
    const int wave = t >> 6;
    const int wr   = wave >> 2;
    const int wc   = wave & 3;
    const int l15  = lane & 15;
    const int g    = lane >> 4;

    const int nwg  = gridDim.x;
    const int per  = nwg >> 3;
    const int mper = per / nbx;
    const int wg   = blockIdx.x;
    const int xcd  = wg & 7;
    const int idx  = wg >> 3;
    const int m0   = (xcd * mper + idx % mper) * 128;
    const int n0   = (idx / mper) * 256;

    const int ntile = K >> 6;

    int srow[2], sblk[2];
#pragma unroll
    for (int r = 0; r < 2; ++r) {
        int s = t * 16 + r * 8192;
        srow[r] = s >> 7;
        int blk = (s >> 4) & 7;
        sblk[r] = blk ^ (srow[r] & 7);
    }
    const int ldst0 = t * 8;

    const bf16* Abase = A  + (size_t)m0 * K;
    const bf16* Bbase = Bt + (size_t)n0 * K;

    const f32x4 z = {0.f, 0.f, 0.f, 0.f};
    f32x4 acc[4][4];
#pragma unroll
    for (int i = 0; i < 4; ++i)
#pragma unroll
        for (int j = 0; j < 4; ++j) acc[i][j] = z;

    auto stageA = [&](int tile, int slot) {
        if (tile >= ntile) return;
        bf16* dst = As + slot * 8192;
        const bf16* src = Abase + tile * 64;
#pragma unroll
        for (int r = 0; r < 2; ++r)
            GLOAD_LDS(src + (size_t)srow[r] * K + sblk[r] * 8,
                      dst + ldst0 + r * 4096);
    };
    auto stageBh = [&](int tile, int slot, int h) {
        if (tile >= ntile) return;
        bf16* dst = Bs + slot * 16384 + h * 8192;
        const bf16* src = Bbase + (size_t)(h * 128) * K + tile * 64;
#pragma unroll
        for (int r = 0; r < 2; ++r)
            GLOAD_LDS(src + (size_t)srow[r] * K + sblk[r] * 8,
                      dst + ldst0 + r * 4096);
    };

#define LOAD_AF(slot)                                                         \
    _Pragma("unroll")                                                         \
    for (int f = 0; f < 4; ++f) {                                             \
        int row = wr * 64 + f * 16 + l15;                                     \
        _Pragma("unroll")                                                     \
        for (int ks = 0; ks < 2; ++ks)                                        \
            af[f][ks] = *(const bf16x8*)(&As[(slot) * 8192 + row * 64 +       \
                            (((ks * 4 + g) ^ (row & 7)) * 8)]);               \
    }
#define LOAD_BF(slot, half, dstv)                                             \
    _Pragma("unroll")                                                         \
    for (int c2 = 0; c2 < 2; ++c2) {                                          \
        int row = wc * 64 + ((half) * 2 + c2) * 16 + l15;                     \
        _Pragma("unroll")                                                     \
        for (int ks = 0; ks < 2; ++ks)                                        \
            dstv[c2][ks] = *(const bf16x8*)(&Bs[(slot) * 16384 + row * 64 +   \
                            (((ks * 4 + g) ^ (row & 7)) * 8)]);               \
    }
#define MFMA_H(bv, half)                                                      \
    {                                                                         \
        __builtin_amdgcn_s_setprio(1);                                        \
        _Pragma("unroll")                                                     \
        for (int f = 0; f < 4; ++f)                                           \
            _Pragma("unroll")                                                 \
            for (int c2 = 0; c2 < 2; ++c2) {                                  \
                acc[f][(half) * 2 + c2] = MFMA16(                             \
                    af[f][0], bv[c2][0], acc[f][(half) * 2 + c2]);            \
                acc[f][(half) * 2 + c2] = MFMA16(                             \
                    af[f][1], bv[c2][1], acc[f][(half) * 2 + c2]);            \
            }                                                                 \
        __builtin_amdgcn_s_setprio(0);                                        \
    }

    stageA(0, 0); stageBh(0, 0, 0); stageBh(0, 0, 1);
    stageA(1, 1); stageBh(1, 1, 0); stageBh(1, 1, 1);
    VMCNT(6);
    BAR();

    int slot = 0;
    for (int T = 0; T < ntile; ++T) {
        int slot2 = slot + 2; if (slot2 >= 3) slot2 -= 3;
        bf16x8 af[4][2], blo[2][2], bhi[2][2];
        LOAD_AF(slot);
        LOAD_BF(slot, 0, blo);
        stageA(T + 2, slot2);
        stageBh(T + 2, slot2, 0);
        MFMA_H(blo, 0);
        BAR();
        LOAD_BF(slot, 1, bhi);
        stageBh(T + 2, slot2, 1);
        MFMA_H(bhi, 1);
        if (T + 1 < ntile) {
            if (T + 2 < ntile) { VMCNT(6); } else { VMCNT(0); }
        }
        BAR();
        slot = (slot == 2) ? 0 : slot + 1;
    }

#undef LOAD_AF
#undef LOAD_BF
#undef MFMA_H

    // ---- epilogue ----
    if (vtg != nullptr && n0 >= 2048) {
        // V block: store transposed into vtg[b*16+h][d][n]
        const int b = m0 >> 11;                 // tile lies in one batch
#pragma unroll
        for (int f = 0; f < 4; ++f) {
            int row = m0 + wr * 64 + f * 16 + g * 4;
            int n   = row & 2047;
#pragma unroll
            for (int cf = 0; cf < 4; ++cf) {
                int col = n0 + wc * 64 + cf * 16 + l15;
                int c2  = col - 2048;
                int h   = c2 >> 6;
                int d   = c2 & 63;
                float bs = bias[col];
                union { bf16 hh[4]; ushort4 u; } s;
#pragma unroll
                for (int r = 0; r < 4; ++r)
                    s.hh[r] = (bf16)(acc[f][cf][r] + bs);
                *(ushort4*)(vtg + (size_t)(b * 16 + h) * 131072 +
                            (size_t)d * 2048 + n) = s.u;
            }
        }
    } else {
#pragma unroll
        for (int f = 0; f < 4; ++f) {
            int row = m0 + wr * 64 + f * 16 + g * 4;
#pragma unroll
            for (int cf = 0; cf < 4; ++cf) {
                int col = n0 + wc * 64 + cf * 16 + l15;
                float bs = bias[col];
                if (col < qcols) bs *= qscale;
#pragma unroll
                for (int r = 0; r < 4; ++r) {
                    float v = acc[f][cf][r] + bs;
                    C[(size_t)(row + r) * ldc + col] = (OutT)v;
                }
            }
        }
    }
}

// ---------------------------------------------------------------------------
// Attention v6b (r10 known-good ~99us) with RS=2048 (qkvb is Q+K only).
// ---------------------------------------------------------------------------
__global__ __launch_bounds__(256, 3) void attn_kernel(
    const bf16* __restrict__ qkv, const bf16* __restrict__ vtg,
    const int* __restrict__ mask, bf16* __restrict__ O)
{
    __shared__ __align__(16) bf16 Ks[2][64 * 64];   // 16 KB [key][d]  xor-swz
    __shared__ __align__(16) bf16 Vt[2][64 * 64];   // 16 KB [d][key]  xor-swz
    __shared__ __align__(16) bf16 Ps[4][16 * 88];   // 11 KB per-wave P
    __shared__ __align__(16) float mneg[2048];      //  8 KB: 0 or -1e30

    const int t    = threadIdx.x;
    const int lane = t & 63;
    const int wave = t >> 6;
    const int l15  = lane & 15;
    const int g    = lane >> 4;

    const int bid = (blockIdx.x & 7) * 128 + (blockIdx.x >> 3);
    const int qt  = bid & 15;
    const int bh  = bid >> 4;
    const int h   = bh & 15;
    const int b   = bh >> 4;
    const int q0  = qt * 128 + wave * 16;           // tile0; tile1 = q0 + 64

    const int* mrow = mask + b * 2048;
    for (int i = t; i < 2048; i += 256)
        mneg[i] = mrow[i] ? 0.0f : -1e30f;

    const size_t RS = 2048;
    const bf16* qp0 = qkv + (size_t)(b * 2048 + q0 + l15) * RS + h * 64 + g * 8;
    const bf16* qp1 = qp0 + (size_t)64 * RS;
    bf16x8 aQ[2][2];
    aQ[0][0] = *(const bf16x8*)(qp0);
    aQ[0][1] = *(const bf16x8*)(qp0 + 32);
    aQ[1][0] = *(const bf16x8*)(qp1);
    aQ[1][1] = *(const bf16x8*)(qp1 + 32);

    const bf16* kbase = qkv + (size_t)(b * 2048) * RS + 1024 + h * 64;
    const bf16* vbase = vtg + (size_t)bh * (64 * 2048);

    const int e0 = t * 8;
    int srow[2], scol[2];
#pragma unroll
    for (int r = 0; r < 2; ++r) {
        int e   = e0 + r * 2048;
        int row = e >> 6;
        int cb  = (e >> 3) & 7;
        srow[r] = row;
        scol[r] = ((cb ^ (row & 7)) * 8);
    }

    const int rb0 = ((g)     ^ (l15 & 7)) * 8;
    const int rb1 = ((4 + g) ^ (l15 & 7)) * 8;

    const f32x4 z = {0.f, 0.f, 0.f, 0.f};
    f32x4 o0[4] = {z, z, z, z}, o1[4] = {z, z, z, z};
    f32x4 lacc0 = z, lacc1 = z;

    bf16x8 ones;
#pragma unroll
    for (int j = 0; j < 8; ++j) ones[j] = (bf16)1.0f;

#pragma unroll
    for (int r = 0; r < 2; ++r) {
        GLOAD_LDS(kbase + (size_t)srow[r] * RS + scol[r],   &Ks[0][e0 + r * 2048]);
        GLOAD_LDS(vbase + (size_t)srow[r] * 2048 + scol[r], &Vt[0][e0 + r * 2048]);
    }
    asm volatile("s_waitcnt vmcnt(0)" ::: "memory");
    __syncthreads();

    for (int i = 0; i < 32; ++i) {
        const int kc  = i * 64;
        const int buf = i & 1;

        if (i + 1 < 32) {
#pragma unroll
            for (int r = 0; r < 2; ++r) {
                GLOAD_LDS(kbase + (size_t)(kc + 64 + srow[r]) * RS + scol[r],
                          &Ks[buf ^ 1][e0 + r * 2048]);
                GLOAD_LDS(vbase + (size_t)srow[r] * 2048 + kc + 64 + scol[r],
                          &Vt[buf ^ 1][e0 + r * 2048]);
            }
        }

        // ---- mask quad per kt: D[row=key=kt*16+g*4+r][col=q] ----
        f32x4 mb4[4];
#pragma unroll
        for (int kt = 0; kt < 4; ++kt)
#pragma unroll
            for (int r = 0; r < 4; ++r)
                mb4[kt][r] = mneg[kc + kt * 16 + g * 4 + r];

        // ---- K fragments, shared by both q-tiles ----
        bf16x8 bk[4][2];
#pragma unroll
        for (int kt = 0; kt < 4; ++kt) {
            const bf16* kr = &Ks[buf][(kt * 16 + l15) * 64];
            bk[kt][0] = *(const bf16x8*)(kr + rb0);
            bk[kt][1] = *(const bf16x8*)(kr + rb1);
        }

        // ---- tile 0: S^T = mfma(K, Q) (mask in C-init), packed P store ----
        f32x4 S[4];
#pragma unroll
        for (int kt = 0; kt < 4; ++kt) {
            S[kt] = MFMA16(bk[kt][0], aQ[0][0], mb4[kt]);
            S[kt] = MFMA16(bk[kt][1], aQ[0][1], S[kt]);
        }
#pragma unroll
        for (int kt = 0; kt < 4; ++kt) {
            union { bf16 hh[4]; ushort4 u; } pk;
#pragma unroll
            for (int r = 0; r < 4; ++r)
                pk.hh[r] = (bf16)__builtin_amdgcn_exp2f(S[kt][r]);
            *(ushort4*)(&Ps[wave][l15 * 88 + kt * 16 + g * 4]) = pk.u;
        }
        asm volatile("s_waitcnt lgkmcnt(0)" ::: "memory");
        __builtin_amdgcn_sched_barrier(0);
        const bf16x8 aP00 = *(const bf16x8*)(&Ps[wave][l15 * 88 + g * 8]);
        const bf16x8 aP01 = *(const bf16x8*)(&Ps[wave][l15 * 88 + 32 + g * 8]);
        asm volatile("s_waitcnt lgkmcnt(0)" ::: "memory");  // aP0 in regs
        __builtin_amdgcn_sched_barrier(0);

        // ---- tile 1: S^T (reusing bk) ----
#pragma unroll
        for (int kt = 0; kt < 4; ++kt) {
            S[kt] = MFMA16(bk[kt][0], aQ[1][0], mb4[kt]);
            S[kt] = MFMA16(bk[kt][1], aQ[1][1], S[kt]);
        }

        // ---- V fragments, read ONCE, shared by both q-tiles ----
        bf16x8 bv[4][2];
#pragma unroll
        for (int dt = 0; dt < 4; ++dt) {
            const bf16* vr = &Vt[buf][(dt * 16 + l15) * 64];
            bv[dt][0] = *(const bf16x8*)(vr + rb0);
            bv[dt][1] = *(const bf16x8*)(vr + rb1);
        }

#pragma unroll
        for (int kt = 0; kt < 4; ++kt) {
            union { bf16 hh[4]; ushort4 u; } pk;
#pragma unroll
            for (int r = 0; r < 4; ++r)
                pk.hh[r] = (bf16)__builtin_amdgcn_exp2f(S[kt][r]);
            *(ushort4*)(&Ps[wave][l15 * 88 + kt * 16 + g * 4]) = pk.u;
        }

        // ---- tile 0 accumulate (overlaps tile-1 P roundtrip) ----
        lacc0 = MFMA16(aP00, ones, lacc0);
        lacc0 = MFMA16(aP01, ones, lacc0);
#pragma unroll
        for (int dt = 0; dt < 4; ++dt) {
            o0[dt] = MFMA16(aP00, bv[dt][0], o0[dt]);
            o0[dt] = MFMA16(aP01, bv[dt][1], o0[dt]);
        }
        asm volatile("s_waitcnt lgkmcnt(0)" ::: "memory");  // P1 committed
        __builtin_amdgcn_sched_barrier(0);
        const bf16x8 aP10 = *(const bf16x8*)(&Ps[wave][l15 * 88 + g * 8]);
        const bf16x8 aP11 = *(const bf16x8*)(&Ps[wave][l15 * 88 + 32 + g * 8]);

        // ---- tile 1 accumulate ----
        lacc1 = MFMA16(aP10, ones, lacc1);
        lacc1 = MFMA16(aP11, ones, lacc1);
#pragma unroll
        for (int dt = 0; dt < 4; ++dt) {
            o1[dt] = MFMA16(aP10, bv[dt][0], o1[dt]);
            o1[dt] = MFMA16(aP11, bv[dt][1], o1[dt]);
        }

        asm volatile("s_waitcnt vmcnt(0)" ::: "memory");  // prefetch landed
        __syncthreads();   // single barrier: buf^1 published, buf reads done
    }

    float inv0[4], inv1[4];
#pragma unroll
    for (int r = 0; r < 4; ++r) {
        inv0[r] = 1.0f / fmaxf(lacc0[r], 1e-30f);
        inv1[r] = 1.0f / fmaxf(lacc1[r], 1e-30f);
    }
#pragma unroll
    for (int nt = 0; nt < 4; ++nt) {
#pragma unroll
        for (int r = 0; r < 4; ++r) {
            int d = nt * 16 + l15;
            int row0 = q0 + g * 4 + r;
            O[(size_t)(b * 2048 + row0) * 1024 + h * 64 + d] = (bf16)(o0[nt][r] * inv0[r]);
            O[(size_t)(b * 2048 + row0 + 64) * 1024 + h * 64 + d] = (bf16)(o1[nt][r] * inv1[r]);
        }
    }
}

// ---------------------------------------------------------------------------
extern "C" void kernel_launch(void* const* d_in, const int* in_sizes, int n_in,
                              void* d_out, int out_size, void* d_ws, size_t ws_size,
                              hipStream_t stream)
{
    const float* x     = (const float*)d_in[0];
    const int*   mask  = (const int*)d_in[1];
    const float* w_qkv = (const float*)d_in[2];
    const float* b_qkv = (const float*)d_in[3];
    const float* w_out = (const float*)d_in[4];
    const float* b_out = (const float*)d_in[5];
    float* out = (float*)d_out;

    char* ws = (char*)d_ws;
    bf16* qkvb  = (bf16*)(ws);                 // 32 MiB: [8192][2048] (Q+K)
    bf16* Obuf  = (bf16*)(ws + 33554432);      // 16 MiB: [8192][1024]
    bf16* xb    = (bf16*)(ws + 50331648);      // 16 MiB: [8192][1024]
    bf16* wqkvT = (bf16*)(ws + 67108864);      //  6 MiB: [3072][1024]
    bf16* woutT = (bf16*)(ws + 73400320);      //  2 MiB: [1024][1024]
    bf16* vtg   = (bf16*)(ws + 75497472);      // 16 MiB: [64 bh][64 d][2048 n]

    prep_kernel<<<dim3(9216), 256, 0, stream>>>(x, xb, w_qkv, wqkvT, w_out, woutT);
    gemm128x256_kernel<bf16><<<dim3(768), 512, 0, stream>>>(
        xb, wqkvT, b_qkv, qkvb, 8192, 2048, 1024, 1024, QSCALE, 12, vtg);
    attn_kernel<<<dim3(1024), 256, 0, stream>>>(qkvb, vtg, mask, Obuf);
    gemm128x256_kernel<float><<<dim3(256), 512, 0, stream>>>(
        Obuf, woutT, b_out, out, 8192, 1024, 1024, 0, 1.0f, 4, nullptr);
}

// Round 16
// 268.429 us; speedup vs baseline: 1.4589x; 1.0238x over previous
//
#include <hip/hip_runtime.h>

// ---------------------------------------------------------------------------
// AttentionMulti: x[4,2048,1024] fp32 -> qkv -> 16-head attention (D=64,
// scale=0.5, key-mask) -> out proj.  Inputs/outputs fp32, mask int32.
// Internal compute in bf16 MFMA.
// r15: vtrans fused into gemm1 epilogue (V written transposed); qkvb [8192][2048].
// r16: attn Ps stride 88 -> 64 with Ks-style XOR swizzle, UNBUNDLED from
// r14's mask-from-global (which cost +6pts VALUBusy and masked the win).
// r14 measured the swizzle's conflict effect: 6.3M -> 4.2M.
// ---------------------------------------------------------------------------

typedef __bf16 bf16;
typedef __attribute__((ext_vector_type(8))) __bf16 bf16x8;
typedef __attribute__((ext_vector_type(4))) float f32x4;

#define MFMA16(a, b, c) __builtin_amdgcn_mfma_f32_16x16x32_bf16(a, b, c, 0, 0, 0)
#define GLOAD_LDS(src, dst) __builtin_amdgcn_global_load_lds( \
    (const __attribute__((address_space(1))) void*)(src),     \
    (__attribute__((address_space(3))) void*)(dst), 16, 0, 0)
#define BAR() __builtin_amdgcn_s_barrier()
#define VMCNT(n) asm volatile("s_waitcnt vmcnt(" #n ")" ::: "memory")

// 0.5 * log2(e): folded into Q (w_qkv cols 0..1023 and b_qkv[0..1023])
#define QSCALE 0.72134752f

// ---------------------------------------------------------------------------
// Fused prologue: cvt x->bf16 (blocks 0..8191) || transpose w_qkv
// (blocks 8192..8959) || transpose w_out (blocks 8960..9215).
// ---------------------------------------------------------------------------
__device__ __forceinline__ void transpose_tile(
    const float* __restrict__ in, bf16* __restrict__ out, int R, int C,
    int scale_rows, float scale, int bx, int by, int t, float (*s)[65])
{
    const int r0 = by * 64;
    const int c0 = bx * 64;
    const int tr  = t >> 4;
    const int tc4 = (t & 15) * 4;
#pragma unroll
    for (int p = 0; p < 4; ++p) {
        int r = tr + p * 16;
        float4 v = *(const float4*)(in + (size_t)(r0 + r) * C + c0 + tc4);
        s[r][tc4 + 0] = v.x; s[r][tc4 + 1] = v.y;
        s[r][tc4 + 2] = v.z; s[r][tc4 + 3] = v.w;
    }
    __syncthreads();
    const int cw  = t >> 3;
    const int rw8 = (t & 7) * 8;
#pragma unroll
    for (int p = 0; p < 2; ++p) {
        int c = cw + p * 32;
        float f = (c0 + c) < scale_rows ? scale : 1.0f;
        union { uint4 v; bf16 h[8]; } u;
#pragma unroll
        for (int j = 0; j < 8; ++j) u.h[j] = (bf16)(s[rw8 + j][c] * f);
        *(uint4*)(out + (size_t)(c0 + c) * R + r0 + rw8) = u.v;
    }
}

__global__ __launch_bounds__(256, 1) void prep_kernel(
    const float* __restrict__ x, bf16* __restrict__ xb,
    const float* __restrict__ w_qkv, bf16* __restrict__ wqkvT,
    const float* __restrict__ w_out, bf16* __restrict__ woutT)
{
    __shared__ float s[64][65];
    const int t = threadIdx.x;
    int blk = blockIdx.x;
    if (blk < 8192) {
        int i = blk * 256 + t;
        float4 v = *(const float4*)(x + (size_t)i * 4);
        union { ushort4 u; bf16 h[4]; } o;
        o.h[0] = (bf16)v.x; o.h[1] = (bf16)v.y;
        o.h[2] = (bf16)v.z; o.h[3] = (bf16)v.w;
        *(ushort4*)(xb + (size_t)i * 4) = o.u;
        return;
    }
    blk -= 8192;
    if (blk < 768) {
        transpose_tile(w_qkv, wqkvT, 1024, 3072, 1024, QSCALE,
                       blk % 48, blk / 48, t, s);
    } else {
        blk -= 768;
        transpose_tile(w_out, woutT, 1024, 1024, 0, 1.0f,
                       blk % 16, blk / 16, t, s);
    }
}

// ---------------------------------------------------------------------------
// 128x256-tile GEMM, BK=64, 3-slot, 2 phases/K-tile (round-10 known-good).
// V-transposed epilogue: if vtg != nullptr and n0 >= 2048, tile stored as
// vtg[b*16+h][d][n] via aligned ushort4 (lane's 4 acc = 4 consecutive n).
// ---------------------------------------------------------------------------
template <typename OutT>
__global__ __launch_bounds__(512, 2) void gemm128x256_kernel(
    const bf16* __restrict__ A, const bf16* __restrict__ Bt,
    const float* __restrict__ bias, OutT* __restrict__ C,
    int M, int ldc, int K, int qcols, float qscale, int nbx,
    bf16* __restrict__ vtg)
{
    __shared__ __align__(16) bf16 As[3 * 128 * 64];   // 48 KiB
    __shared__ __align__(16) bf16 Bs[3 * 256 * 64];   // 96 KiB

    const int t    = threadIdx.x;
    const int lane = t & 63;
    const int wave = t >> 6;
    const int wr   = wave >> 2;
    const int wc   = wave & 3;
    const int l15  = lane & 15;
    const int g    = lane >> 4;

    const int nwg  = gridDim.x;
    const int per  = nwg >> 3;
    const int mper = per / nbx;
    const int wg   = blockIdx.x;
    const int xcd  = wg & 7;
    const int idx  = wg >> 3;
    const int m0   = (xcd * mper + idx % mper) * 128;
    const int n0   = (idx / mper) * 256;

    const int ntile = K >> 6;

    int srow[2], sblk[2];
#pragma unroll
    for (int r = 0; r < 2; ++r) {
        int s = t * 16 + r * 8192;
        srow[r] = s >> 7;
        int blk = (s >> 4) & 7;
        sblk[r] = blk ^ (srow[r] & 7);
    }
    const int ldst0 = t * 8;

    const bf16* Abase = A  + (size_t)m0 * K;
    const bf16* Bbase = Bt + (size_t)n0 * K;

    const f32x4 z = {0.f, 0.f, 0.f, 0.f};
    f32x4 acc[4][4];
#pragma unroll
    for (int i = 0; i < 4; ++i)
#pragma unroll
        for (int j = 0; j < 4; ++j) acc[i][j] = z;

    auto stageA = [&](int tile, int slot) {
        if (tile >= ntile) return;
        bf16* dst = As + slot * 8192;
        const bf16* src = Abase + tile * 64;
#pragma unroll
        for (int r = 0; r < 2; ++r)
            GLOAD_LDS(src + (size_t)srow[r] * K + sblk[r] * 8,
                      dst + ldst0 + r * 4096);
    };
    auto stageBh = [&](int tile, int slot, int h) {
        if (tile >= ntile) return;
        bf16* dst = Bs + slot * 16384 + h * 8192;
        const bf16* src = Bbase + (size_t)(h * 128) * K + tile * 64;
#pragma unroll
        for (int r = 0; r < 2; ++r)
            GLOAD_LDS(src + (size_t)srow[r] * K + sblk[r] * 8,
                      dst + ldst0 + r * 4096);
    };

#define LOAD_AF(slot)                                                         \
    _Pragma("unroll")                                                         \
    for (int f = 0; f < 4; ++f) {                                             \
        int row = wr * 64 + f * 16 + l15;                                     \
        _Pragma("unroll")                                                     \
        for (int ks = 0; ks < 2; ++ks)                                        \
            af[f][ks] = *(const bf16x8*)(&As[(slot) * 8192 + row * 64 +       \
                            (((ks * 4 + g) ^ (row & 7)) * 8)]);               \
    }
#define LOAD_BF(slot, half, dstv)                                             \
    _Pragma("unroll")                                                         \
    for (int c2 = 0; c2 < 2; ++c2) {                                          \
        int row = wc * 64 + ((half) * 2 + c2) * 16 + l15;                     \
        _Pragma("unroll")                                                     \
        for (int ks = 0; ks < 2; ++ks)                                        \
            dstv[c2][ks] = *(const bf16x8*)(&Bs[(slot) * 16384 + row * 64 +   \
                            (((ks * 4 + g) ^ (row & 7)) * 8)]);               \
    }
#define MFMA_H(bv, half)                                                      \
    {                                                                         \
        __builtin_amdgcn_s_setprio(1);                                        \
        _Pragma("unroll")                                                     \
        for (int f = 0; f < 4; ++f)                                           \
            _Pragma("unroll")                                                 \
            for (int c2 = 0; c2 < 2; ++c2) {                                  \
                acc[f][(half) * 2 + c2] = MFMA16(                             \
                    af[f][0], bv[c2][0], acc[f][(half) * 2 + c2]);            \
                acc[f][(half) * 2 + c2] = MFMA16(                             \
                    af[f][1], bv[c2][1], acc[f][(half) * 2 + c2]);            \
            }                                                                 \
        __builtin_amdgcn_s_setprio(0);                                        \
    }

    stageA(0, 0); stageBh(0, 0, 0); stageBh(0, 0, 1);
    stageA(1, 1); stageBh(1, 1, 0); stageBh(1, 1, 1);
    VMCNT(6);
    BAR();

    int slot = 0;
    for (int T = 0; T < ntile; ++T) {
        int slot2 = slot + 2; if (slot2 >= 3) slot2 -= 3;
        bf16x8 af[4][2], blo[2][2], bhi[2][2];
        LOAD_AF(slot);
        LOAD_BF(slot, 0, blo);
        stageA(T + 2, slot2);
        stageBh(T + 2, slot2, 0);
        MFMA_H(blo, 0);
        BAR();
        LOAD_BF(slot, 1, bhi);
        stageBh(T + 2, slot2, 1);
        MFMA_H(bhi, 1);
        if (T + 1 < ntile) {
            if (T + 2 < ntile) { VMCNT(6); } else { VMCNT(0); }
        }
        BAR();
        slot = (slot == 2) ? 0 : slot + 1;
    }

#undef LOAD_AF
#undef LOAD_BF
#undef MFMA_H

    // ---- epilogue ----
    if (vtg != nullptr && n0 >= 2048) {
        const int b = m0 >> 11;
#pragma unroll
        for (int f = 0; f < 4; ++f) {
            int row = m0 + wr * 64 + f * 16 + g * 4;
            int n   = row & 2047;
#pragma unroll
            for (int cf = 0; cf < 4; ++cf) {
                int col = n0 + wc * 64 + cf * 16 + l15;
                int c2  = col - 2048;
                int h   = c2 >> 6;
                int d   = c2 & 63;
                float bs = bias[col];
                union { bf16 hh[4]; ushort4 u; } s;
#pragma unroll
                for (int r = 0; r < 4; ++r)
                    s.hh[r] = (bf16)(acc[f][cf][r] + bs);
                *(ushort4*)(vtg + (size_t)(b * 16 + h) * 131072 +
                            (size_t)d * 2048 + n) = s.u;
            }
        }
    } else {
#pragma unroll
        for (int f = 0; f < 4; ++f) {
            int row = m0 + wr * 64 + f * 16 + g * 4;
#pragma unroll
            for (int cf = 0; cf < 4; ++cf) {
                int col = n0 + wc * 64 + cf * 16 + l15;
                float bs = bias[col];
                if (col < qcols) bs *= qscale;
#pragma unroll
                for (int r = 0; r < 4; ++r) {
                    float v = acc[f][cf][r] + bs;
                    C[(size_t)(row + r) * ldc + col] = (OutT)v;
                }
            }
        }
    }
}

// ---------------------------------------------------------------------------
// Attention v6c: v6b (mneg in LDS, RS=2048) + Ps stride 88 -> 64 with the
// Ks-style XOR block swizzle.  Write: ushort4 at block (kt*2+(g>>1))^(l15&7)
// + (g&1)*4; read: b128 at rb0/rb1 -- both conflict-reduced (r14 measured
// 6.3M -> 4.2M on this exact layout).  LDS 49152 (3 blocks/CU unchanged).
// ---------------------------------------------------------------------------
__global__ __launch_bounds__(256, 3) void attn_kernel(
    const bf16* __restrict__ qkv, const bf16* __restrict__ vtg,
    const int* __restrict__ mask, bf16* __restrict__ O)
{
    __shared__ __align__(16) bf16 Ks[2][64 * 64];   // 16 KB [key][d]  xor-swz
    __shared__ __align__(16) bf16 Vt[2][64 * 64];   // 16 KB [d][key]  xor-swz
    __shared__ __align__(16) bf16 Ps[4][16 * 64];   //  8 KB per-wave P, xor-swz
    __shared__ __align__(16) float mneg[2048];      //  8 KB: 0 or -1e30

    const int t    = threadIdx.x;
    const int lane = t & 63;
    const int wave = t >> 6;
    const int l15  = lane & 15;
    const int g    = lane >> 4;

    const int bid = (blockIdx.x & 7) * 128 + (blockIdx.x >> 3);
    const int qt  = bid & 15;
    const int bh  = bid >> 4;
    const int h   = bh & 15;
    const int b   = bh >> 4;
    const int q0  = qt * 128 + wave * 16;           // tile0; tile1 = q0 + 64

    const int* mrow = mask + b * 2048;
    for (int i = t; i < 2048; i += 256)
        mneg[i] = mrow[i] ? 0.0f : -1e30f;

    const size_t RS = 2048;
    const bf16* qp0 = qkv + (size_t)(b * 2048 + q0 + l15) * RS + h * 64 + g * 8;
    const bf16* qp1 = qp0 + (size_t)64 * RS;
    bf16x8 aQ[2][2];
    aQ[0][0] = *(const bf16x8*)(qp0);
    aQ[0][1] = *(const bf16x8*)(qp0 + 32);
    aQ[1][0] = *(const bf16x8*)(qp1);
    aQ[1][1] = *(const bf16x8*)(qp1 + 32);

    const bf16* kbase = qkv + (size_t)(b * 2048) * RS + 1024 + h * 64;
    const bf16* vbase = vtg + (size_t)bh * (64 * 2048);

    const int e0 = t * 8;
    int srow[2], scol[2];
#pragma unroll
    for (int r = 0; r < 2; ++r) {
        int e   = e0 + r * 2048;
        int row = e >> 6;
        int cb  = (e >> 3) & 7;
        srow[r] = row;
        scol[r] = ((cb ^ (row & 7)) * 8);
    }

    const int rb0 = ((g)     ^ (l15 & 7)) * 8;
    const int rb1 = ((4 + g) ^ (l15 & 7)) * 8;
    // swizzled P-store offsets (8B slots), one per kt
    int pw[4];
#pragma unroll
    for (int kt = 0; kt < 4; ++kt)
        pw[kt] = l15 * 64 + (((kt * 2 + (g >> 1)) ^ (l15 & 7)) * 8) + (g & 1) * 4;

    const f32x4 z = {0.f, 0.f, 0.f, 0.f};
    f32x4 o0[4] = {z, z, z, z}, o1[4] = {z, z, z, z};
    f32x4 lacc0 = z, lacc1 = z;

    bf16x8 ones;
#pragma unroll
    for (int j = 0; j < 8; ++j) ones[j] = (bf16)1.0f;

#pragma unroll
    for (int r = 0; r < 2; ++r) {
        GLOAD_LDS(kbase + (size_t)srow[r] * RS + scol[r],   &Ks[0][e0 + r * 2048]);
        GLOAD_LDS(vbase + (size_t)srow[r] * 2048 + scol[r], &Vt[0][e0 + r * 2048]);
    }
    asm volatile("s_waitcnt vmcnt(0)" ::: "memory");
    __syncthreads();

    for (int i = 0; i < 32; ++i) {
        const int kc  = i * 64;
        const int buf = i & 1;

        if (i + 1 < 32) {
#pragma unroll
            for (int r = 0; r < 2; ++r) {
                GLOAD_LDS(kbase + (size_t)(kc + 64 + srow[r]) * RS + scol[r],
                          &Ks[buf ^ 1][e0 + r * 2048]);
                GLOAD_LDS(vbase + (size_t)srow[r] * 2048 + kc + 64 + scol[r],
                          &Vt[buf ^ 1][e0 + r * 2048]);
            }
        }

        // ---- mask quad per kt: D[row=key=kt*16+g*4+r][col=q] ----
        f32x4 mb4[4];
#pragma unroll
        for (int kt = 0; kt < 4; ++kt)
#pragma unroll
            for (int r = 0; r < 4; ++r)
                mb4[kt][r] = mneg[kc + kt * 16 + g * 4 + r];

        // ---- K fragments, shared by both q-tiles ----
        bf16x8 bk[4][2];
#pragma unroll
        for (int kt = 0; kt < 4; ++kt) {
            const bf16* kr = &Ks[buf][(kt * 16 + l15) * 64];
            bk[kt][0] = *(const bf16x8*)(kr + rb0);
            bk[kt][1] = *(const bf16x8*)(kr + rb1);
        }

        // ---- tile 0: S^T = mfma(K, Q) (mask in C-init), packed P store ----
        f32x4 S[4];
#pragma unroll
        for (int kt = 0; kt < 4; ++kt) {
            S[kt] = MFMA16(bk[kt][0], aQ[0][0], mb4[kt]);
            S[kt] = MFMA16(bk[kt][1], aQ[0][1], S[kt]);
        }
#pragma unroll
        for (int kt = 0; kt < 4; ++kt) {
            union { bf16 hh[4]; ushort4 u; } pk;
#pragma unroll
            for (int r = 0; r < 4; ++r)
                pk.hh[r] = (bf16)__builtin_amdgcn_exp2f(S[kt][r]);
            *(ushort4*)(&Ps[wave][pw[kt]]) = pk.u;
        }
        asm volatile("s_waitcnt lgkmcnt(0)" ::: "memory");
        __builtin_amdgcn_sched_barrier(0);
        const bf16x8 aP00 = *(const bf16x8*)(&Ps[wave][l15 * 64 + rb0]);
        const bf16x8 aP01 = *(const bf16x8*)(&Ps[wave][l15 * 64 + rb1]);
        asm volatile("s_waitcnt lgkmcnt(0)" ::: "memory");  // aP0 in regs
        __builtin_amdgcn_sched_barrier(0);

        // ---- tile 1: S^T (reusing bk) ----
#pragma unroll
        for (int kt = 0; kt < 4; ++kt) {
            S[kt] = MFMA16(bk[kt][0], aQ[1][0], mb4[kt]);
            S[kt] = MFMA16(bk[kt][1], aQ[1][1], S[kt]);
        }

        // ---- V fragments, read ONCE, shared by both q-tiles ----
        bf16x8 bv[4][2];
#pragma unroll
        for (int dt = 0; dt < 4; ++dt) {
            const bf16* vr = &Vt[buf][(dt * 16 + l15) * 64];
            bv[dt][0] = *(const bf16x8*)(vr + rb0);
            bv[dt][1] = *(const bf16x8*)(vr + rb1);
        }

#pragma unroll
        for (int kt = 0; kt < 4; ++kt) {
            union { bf16 hh[4]; ushort4 u; } pk;
#pragma unroll
            for (int r = 0; r < 4; ++r)
                pk.hh[r] = (bf16)__builtin_amdgcn_exp2f(S[kt][r]);
            *(ushort4*)(&Ps[wave][pw[kt]]) = pk.u;
        }

        // ---- tile 0 accumulate (overlaps tile-1 P roundtrip) ----
        lacc0 = MFMA16(aP00, ones, lacc0);
        lacc0 = MFMA16(aP01, ones, lacc0);
#pragma unroll
        for (int dt = 0; dt < 4; ++dt) {
            o0[dt] = MFMA16(aP00, bv[dt][0], o0[dt]);
            o0[dt] = MFMA16(aP01, bv[dt][1], o0[dt]);
        }
        asm volatile("s_waitcnt lgkmcnt(0)" ::: "memory");  // P1 committed
        __builtin_amdgcn_sched_barrier(0);
        const bf16x8 aP10 = *(const bf16x8*)(&Ps[wave][l15 * 64 + rb0]);
        const bf16x8 aP11 = *(const bf16x8*)(&Ps[wave][l15 * 64 + rb1]);

        // ---- tile 1 accumulate ----
        lacc1 = MFMA16(aP10, ones, lacc1);
        lacc1 = MFMA16(aP11, ones, lacc1);
#pragma unroll
        for (int dt = 0; dt < 4; ++dt) {
            o1[dt] = MFMA16(aP10, bv[dt][0], o1[dt]);
            o1[dt] = MFMA16(aP11, bv[dt][1], o1[dt]);
        }

        asm volatile("s_waitcnt vmcnt(0)" ::: "memory");  // prefetch landed
        __syncthreads();   // single barrier: buf^1 published, buf reads done
    }

    float inv0[4], inv1[4];
#pragma unroll
    for (int r = 0; r < 4; ++r) {
        inv0[r] = 1.0f / fmaxf(lacc0[r], 1e-30f);
        inv1[r] = 1.0f / fmaxf(lacc1[r], 1e-30f);
    }
#pragma unroll
    for (int nt = 0; nt < 4; ++nt) {
#pragma unroll
        for (int r = 0; r < 4; ++r) {
            int d = nt * 16 + l15;
            int row0 = q0 + g * 4 + r;
            O[(size_t)(b * 2048 + row0) * 1024 + h * 64 + d] = (bf16)(o0[nt][r] * inv0[r]);
            O[(size_t)(b * 2048 + row0 + 64) * 1024 + h * 64 + d] = (bf16)(o1[nt][r] * inv1[r]);
        }
    }
}

// ---------------------------------------------------------------------------
extern "C" void kernel_launch(void* const* d_in, const int* in_sizes, int n_in,
                              void* d_out, int out_size, void* d_ws, size_t ws_size,
                              hipStream_t stream)
{
    const float* x     = (const float*)d_in[0];
    const int*   mask  = (const int*)d_in[1];
    const float* w_qkv = (const float*)d_in[2];
    const float* b_qkv = (const float*)d_in[3];
    const float* w_out = (const float*)d_in[4];
    const float* b_out = (const float*)d_in[5];
    float* out = (float*)d_out;

    char* ws = (char*)d_ws;
    bf16* qkvb  = (bf16*)(ws);                 // 32 MiB: [8192][2048] (Q+K)
    bf16* Obuf  = (bf16*)(ws + 33554432);      // 16 MiB: [8192][1024]
    bf16* xb    = (bf16*)(ws + 50331648);      // 16 MiB: [8192][1024]
    bf16* wqkvT = (bf16*)(ws + 67108864);      //  6 MiB: [3072][1024]
    bf16* woutT = (bf16*)(ws + 73400320);      //  2 MiB: [1024][1024]
    bf16* vtg   = (bf16*)(ws + 75497472);      // 16 MiB: [64 bh][64 d][2048 n]

    prep_kernel<<<dim3(9216), 256, 0, stream>>>(x, xb, w_qkv, wqkvT, w_out, woutT);
    gemm128x256_kernel<bf16><<<dim3(768), 512, 0, stream>>>(
        xb, wqkvT, b_qkv, qkvb, 8192, 2048, 1024, 1024, QSCALE, 12, vtg);
    attn_kernel<<<dim3(1024), 256, 0, stream>>>(qkvb, vtg, mask, Obuf);
    gemm128x256_kernel<float><<<dim3(256), 512, 0, stream>>>(
        Obuf, woutT, b_out, out, 8192, 1024, 1024, 0, 1.0f, 4, nullptr);
}

// Round 17
// 251.191 us; speedup vs baseline: 1.5590x; 1.0686x over previous
//
#include <hip/hip_runtime.h>

// ---------------------------------------------------------------------------
// AttentionMulti: x[4,2048,1024] fp32 -> qkv -> 16-head attention (D=64,
// scale=0.5, key-mask) -> out proj.  Inputs/outputs fp32, mask int32.
// Internal compute in bf16 MFMA.
// r15: vtrans fused into gemm1 epilogue; qkvb [8192][2048].
// r16: attn Ps XOR swizzle (conflicts 6.3M->4.2M), 268.4us.
// r17: P LDS-roundtrip DELETED (r7's reg-PV with both failure modes fixed):
//   - vtg written with rho key-permutation at gemm1 epilogue (free) ->
//     attn PV A-fragment is ONE contiguous b128 (r7 used 2x b64: regressed).
//   - denominator via mfma(ones, pb) on matrix pipe (r7 used scalar dsum).
//   Ps buffer + 3 serializing lgkmcnt(0) chains per chunk deleted.
// ---------------------------------------------------------------------------

typedef __bf16 bf16;
typedef __attribute__((ext_vector_type(8))) __bf16 bf16x8;
typedef __attribute__((ext_vector_type(4))) float f32x4;

#define MFMA16(a, b, c) __builtin_amdgcn_mfma_f32_16x16x32_bf16(a, b, c, 0, 0, 0)
#define GLOAD_LDS(src, dst) __builtin_amdgcn_global_load_lds( \
    (const __attribute__((address_space(1))) void*)(src),     \
    (__attribute__((address_space(3))) void*)(dst), 16, 0, 0)
#define BAR() __builtin_amdgcn_s_barrier()
#define VMCNT(n) asm volatile("s_waitcnt vmcnt(" #n ")" ::: "memory")

// 0.5 * log2(e): folded into Q (w_qkv cols 0..1023 and b_qkv[0..1023])
#define QSCALE 0.72134752f

// ---------------------------------------------------------------------------
// Fused prologue: cvt x->bf16 (blocks 0..8191) || transpose w_qkv
// (blocks 8192..8959) || transpose w_out (blocks 8960..9215).
// ---------------------------------------------------------------------------
__device__ __forceinline__ void transpose_tile(
    const float* __restrict__ in, bf16* __restrict__ out, int R, int C,
    int scale_rows, float scale, int bx, int by, int t, float (*s)[65])
{
    const int r0 = by * 64;
    const int c0 = bx * 64;
    const int tr  = t >> 4;
    const int tc4 = (t & 15) * 4;
#pragma unroll
    for (int p = 0; p < 4; ++p) {
        int r = tr + p * 16;
        float4 v = *(const float4*)(in + (size_t)(r0 + r) * C + c0 + tc4);
        s[r][tc4 + 0] = v.x; s[r][tc4 + 1] = v.y;
        s[r][tc4 + 2] = v.z; s[r][tc4 + 3] = v.w;
    }
    __syncthreads();
    const int cw  = t >> 3;
    const int rw8 = (t & 7) * 8;
#pragma unroll
    for (int p = 0; p < 2; ++p) {
        int c = cw + p * 32;
        float f = (c0 + c) < scale_rows ? scale : 1.0f;
        union { uint4 v; bf16 h[8]; } u;
#pragma unroll
        for (int j = 0; j < 8; ++j) u.h[j] = (bf16)(s[rw8 + j][c] * f);
        *(uint4*)(out + (size_t)(c0 + c) * R + r0 + rw8) = u.v;
    }
}

__global__ __launch_bounds__(256, 1) void prep_kernel(
    const float* __restrict__ x, bf16* __restrict__ xb,
    const float* __restrict__ w_qkv, bf16* __restrict__ wqkvT,
    const float* __restrict__ w_out, bf16* __restrict__ woutT)
{
    __shared__ float s[64][65];
    const int t = threadIdx.x;
    int blk = blockIdx.x;
    if (blk < 8192) {
        int i = blk * 256 + t;
        float4 v = *(const float4*)(x + (size_t)i * 4);
        union { ushort4 u; bf16 h[4]; } o;
        o.h[0] = (bf16)v.x; o.h[1] = (bf16)v.y;
        o.h[2] = (bf16)v.z; o.h[3] = (bf16)v.w;
        *(ushort4*)(xb + (size_t)i * 4) = o.u;
        return;
    }
    blk -= 8192;
    if (blk < 768) {
        transpose_tile(w_qkv, wqkvT, 1024, 3072, 1024, QSCALE,
                       blk % 48, blk / 48, t, s);
    } else {
        blk -= 768;
        transpose_tile(w_out, woutT, 1024, 1024, 0, 1.0f,
                       blk % 16, blk / 16, t, s);
    }
}

// ---------------------------------------------------------------------------
// 128x256-tile GEMM, BK=64, 3-slot, 2 phases/K-tile (round-10 known-good).
// V-transposed epilogue (vtg != nullptr, n0 >= 2048): stores as
// vtg[b*16+h][d][perm(n)] where perm applies the PV rho key-permutation
// within each 32-key group (k<16 -> (k>>2)*8, else ((k-16)>>2)*8+4; the
// 4-aligned quad stays one contiguous ushort4 -> zero extra cost).
// ---------------------------------------------------------------------------
template <typename OutT>
__global__ __launch_bounds__(512, 2) void gemm128x256_kernel(
    const bf16* __restrict__ A, const bf16* __restrict__ Bt,
    const float* __restrict__ bias, OutT* __restrict__ C,
    int M, int ldc, int K, int qcols, float qscale, int nbx,
    bf16* __restrict__ vtg)
{
    __shared__ __align__(16) bf16 As[3 * 128 * 64];   // 48 KiB
    __shared__ __align__(16) bf16 Bs[3 * 256 * 64];   // 96 KiB

    const int t    = threadIdx.x;
    const int lane = t & 63;
    const int wave = t >> 6;
    const int wr   = wave >> 2;
    const int wc   = wave & 3;
    const int l15  = lane & 15;
    const int g    = lane >> 4;

    const int nwg  = gridDim.x;
    const int per  = nwg >> 3;
    const int mper = per / nbx;
    const int wg   = blockIdx.x;
    const int xcd  = wg & 7;
    const int idx  = wg >> 3;
    const int m0   = (xcd * mper + idx % mper) * 128;
    const int n0   = (idx / mper) * 256;

    const int ntile = K >> 6;

    int srow[2], sblk[2];
#pragma unroll
    for (int r = 0; r < 2; ++r) {
        int s = t * 16 + r * 8192;
        srow[r] = s >> 7;
        int blk = (s >> 4) & 7;
        sblk[r] = blk ^ (srow[r] & 7);
    }
    const int ldst0 = t * 8;

    const bf16* Abase = A  + (size_t)m0 * K;
    const bf16* Bbase = Bt + (size_t)n0 * K;

    const f32x4 z = {0.f, 0.f, 0.f, 0.f};
    f32x4 acc[4][4];
#pragma unroll
    for (int i = 0; i < 4; ++i)
#pragma unroll
        for (int j = 0; j < 4; ++j) acc[i][j] = z;

    auto stageA = [&](int tile, int slot) {
        if (tile >= ntile) return;
        bf16* dst = As + slot * 8192;
        const bf16* src = Abase + tile * 64;
#pragma unroll
        for (int r = 0; r < 2; ++r)
            GLOAD_LDS(src + (size_t)srow[r] * K + sblk[r] * 8,
                      dst + ldst0 + r * 4096);
    };
    auto stageBh = [&](int tile, int slot, int h) {
        if (tile >= ntile) return;
        bf16* dst = Bs + slot * 16384 + h * 8192;
        const bf16* src = Bbase + (size_t)(h * 128) * K + tile * 64;
#pragma unroll
        for (int r = 0; r < 2; ++r)
            GLOAD_LDS(src + (size_t)srow[r] * K + sblk[r] * 8,
                      dst + ldst0 + r * 4096);
    };

#define LOAD_AF(slot)                                                         \
    _Pragma("unroll")                                                         \
    for (int f = 0; f < 4; ++f) {                                             \
        int row = wr * 64 + f * 16 + l15;                                     \
        _Pragma("unroll")                                                     \
        for (int ks = 0; ks < 2; ++ks)                                        \
            af[f][ks] = *(const bf16x8*)(&As[(slot) * 8192 + row * 64 +       \
                            (((ks * 4 + g) ^ (row & 7)) * 8)]);               \
    }
#define LOAD_BF(slot, half, dstv)                                             \
    _Pragma("unroll")                                                         \
    for (int c2 = 0; c2 < 2; ++c2) {                                          \
        int row = wc * 64 + ((half) * 2 + c2) * 16 + l15;                     \
        _Pragma("unroll")                                                     \
        for (int ks = 0; ks < 2; ++ks)                                        \
            dstv[c2][ks] = *(const bf16x8*)(&Bs[(slot) * 16384 + row * 64 +   \
                            (((ks * 4 + g) ^ (row & 7)) * 8)]);               \
    }
#define MFMA_H(bv, half)                                                      \
    {                                                                         \
        __builtin_amdgcn_s_setprio(1);                                        \
        _Pragma("unroll")                                                     \
        for (int f = 0; f < 4; ++f)                                           \
            _Pragma("unroll")                                                 \
            for (int c2 = 0; c2 < 2; ++c2) {                                  \
                acc[f][(half) * 2 + c2] = MFMA16(                             \
                    af[f][0], bv[c2][0], acc[f][(half) * 2 + c2]);            \
                acc[f][(half) * 2 + c2] = MFMA16(                             \
                    af[f][1], bv[c2][1], acc[f][(half) * 2 + c2]);            \
            }                                                                 \
        __builtin_amdgcn_s_setprio(0);                                        \
    }

    stageA(0, 0); stageBh(0, 0, 0); stageBh(0, 0, 1);
    stageA(1, 1); stageBh(1, 1, 0); stageBh(1, 1, 1);
    VMCNT(6);
    BAR();

    int slot = 0;
    for (int T = 0; T < ntile; ++T) {
        int slot2 = slot + 2; if (slot2 >= 3) slot2 -= 3;
        bf16x8 af[4][2], blo[2][2], bhi[2][2];
        LOAD_AF(slot);
        LOAD_BF(slot, 0, blo);
        stageA(T + 2, slot2);
        stageBh(T + 2, slot2, 0);
        MFMA_H(blo, 0);
        BAR();
        LOAD_BF(slot, 1, bhi);
        stageBh(T + 2, slot2, 1);
        MFMA_H(bhi, 1);
        if (T + 1 < ntile) {
            if (T + 2 < ntile) { VMCNT(6); } else { VMCNT(0); }
        }
        BAR();
        slot = (slot == 2) ? 0 : slot + 1;
    }

#undef LOAD_AF
#undef LOAD_BF
#undef MFMA_H

    // ---- epilogue ----
    if (vtg != nullptr && n0 >= 2048) {
        const int b = m0 >> 11;
#pragma unroll
        for (int f = 0; f < 4; ++f) {
            int row = m0 + wr * 64 + f * 16 + g * 4;
            int n   = row & 2047;                 // 4-aligned
            int k   = n & 31;
            int pos = (k < 16) ? ((k >> 2) * 8) : (((k - 16) >> 2) * 8 + 4);
            int np  = (n & ~31) + pos;            // rho-permuted n
#pragma unroll
            for (int cf = 0; cf < 4; ++cf) {
                int col = n0 + wc * 64 + cf * 16 + l15;
                int c2  = col - 2048;
                int h   = c2 >> 6;
                int d   = c2 & 63;
                float bs = bias[col];
                union { bf16 hh[4]; ushort4 u; } s;
#pragma unroll
                for (int r = 0; r < 4; ++r)
                    s.hh[r] = (bf16)(acc[f][cf][r] + bs);
                *(ushort4*)(vtg + (size_t)(b * 16 + h) * 131072 +
                            (size_t)d * 2048 + np) = s.u;
            }
        }
    } else {
#pragma unroll
        for (int f = 0; f < 4; ++f) {
            int row = m0 + wr * 64 + f * 16 + g * 4;
#pragma unroll
            for (int cf = 0; cf < 4; ++cf) {
                int col = n0 + wc * 64 + cf * 16 + l15;
                float bs = bias[col];
                if (col < qcols) bs *= qscale;
#pragma unroll
                for (int r = 0; r < 4; ++r) {
                    float v = acc[f][cf][r] + bs;
                    C[(size_t)(row + r) * ldc + col] = (OutT)v;
                }
            }
        }
    }
}

// ---------------------------------------------------------------------------
// Attention v9: reg-PV, no P LDS-roundtrip.
//  - QK^T swapped (proven r6): lane (g,l15) reg r of kt holds
//    P[key=kt*16+4g+r][q=l15].
//  - pb[m] = {exp2(S[2m][0..3]), exp2(S[2m+1][0..3])} is EXACTLY the PV
//    B-operand for the rho key-mapping (validated end-to-end in r7).
//  - V pre-permuted by rho in vtg (gemm1 epilogue) -> A-fragment is ONE
//    contiguous b128 at ((m*4+g)^(l15&7))*8 (same bank pattern as the
//    proven bv reads; r7's 2x b64 was the regression).
//  - Denominator: lacc = mfma(ones, pb[m], lacc) -> colsum per q (matrix
//    pipe; r7's scalar dsum was the other regression).
//  - Output O^T: lane stores ushort4 per dt at O[q0+l15][h*64+dt*16+g*4].
//  LDS 40960 (Ps deleted); 16 b128 reads/chunk/wave (was 20 + 8 b64 + 3
//  serializing lgkmcnt(0) chains).
// ---------------------------------------------------------------------------
__global__ __launch_bounds__(256, 3) void attn_kernel(
    const bf16* __restrict__ qkv, const bf16* __restrict__ vtg,
    const int* __restrict__ mask, bf16* __restrict__ O)
{
    __shared__ __align__(16) bf16 Ks[2][64 * 64];   // 16 KB [key][d]  xor-swz
    __shared__ __align__(16) bf16 Vt[2][64 * 64];   // 16 KB [d][key-perm] swz
    __shared__ __align__(16) float mneg[2048];      //  8 KB: 0 or -1e30

    const int t    = threadIdx.x;
    const int lane = t & 63;
    const int wave = t >> 6;
    const int l15  = lane & 15;
    const int g    = lane >> 4;

    const int bid = (blockIdx.x & 7) * 128 + (blockIdx.x >> 3);
    const int qt  = bid & 15;
    const int bh  = bid >> 4;
    const int h   = bh & 15;
    const int b   = bh >> 4;
    const int q0  = qt * 128 + wave * 16;           // tile0; tile1 = q0 + 64

    const int* mrow = mask + b * 2048;
    for (int i = t; i < 2048; i += 256)
        mneg[i] = mrow[i] ? 0.0f : -1e30f;

    const size_t RS = 2048;
    const bf16* qp0 = qkv + (size_t)(b * 2048 + q0 + l15) * RS + h * 64 + g * 8;
    const bf16* qp1 = qp0 + (size_t)64 * RS;
    bf16x8 aQ[2][2];
    aQ[0][0] = *(const bf16x8*)(qp0);
    aQ[0][1] = *(const bf16x8*)(qp0 + 32);
    aQ[1][0] = *(const bf16x8*)(qp1);
    aQ[1][1] = *(const bf16x8*)(qp1 + 32);

    const bf16* kbase = qkv + (size_t)(b * 2048) * RS + 1024 + h * 64;
    const bf16* vbase = vtg + (size_t)bh * (64 * 2048);

    const int e0 = t * 8;
    int srow[2], scol[2];
#pragma unroll
    for (int r = 0; r < 2; ++r) {
        int e   = e0 + r * 2048;
        int row = e >> 6;
        int cb  = (e >> 3) & 7;
        srow[r] = row;
        scol[r] = ((cb ^ (row & 7)) * 8);
    }

    const int rb0 = ((g)     ^ (l15 & 7)) * 8;
    const int rb1 = ((4 + g) ^ (l15 & 7)) * 8;
    const int vb0 = ((g)     ^ (l15 & 7)) * 8;      // m=0 V-frag block
    const int vb1 = ((4 + g) ^ (l15 & 7)) * 8;      // m=1 V-frag block

    const f32x4 z = {0.f, 0.f, 0.f, 0.f};
    f32x4 o0[4] = {z, z, z, z}, o1[4] = {z, z, z, z};
    f32x4 lacc0 = z, lacc1 = z;

    bf16x8 ones;
#pragma unroll
    for (int j = 0; j < 8; ++j) ones[j] = (bf16)1.0f;

#pragma unroll
    for (int r = 0; r < 2; ++r) {
        GLOAD_LDS(kbase + (size_t)srow[r] * RS + scol[r],   &Ks[0][e0 + r * 2048]);
        GLOAD_LDS(vbase + (size_t)srow[r] * 2048 + scol[r], &Vt[0][e0 + r * 2048]);
    }
    asm volatile("s_waitcnt vmcnt(0)" ::: "memory");
    __syncthreads();

    for (int i = 0; i < 32; ++i) {
        const int kc  = i * 64;
        const int buf = i & 1;

        if (i + 1 < 32) {
#pragma unroll
            for (int r = 0; r < 2; ++r) {
                GLOAD_LDS(kbase + (size_t)(kc + 64 + srow[r]) * RS + scol[r],
                          &Ks[buf ^ 1][e0 + r * 2048]);
                GLOAD_LDS(vbase + (size_t)srow[r] * 2048 + kc + 64 + scol[r],
                          &Vt[buf ^ 1][e0 + r * 2048]);
            }
        }

        // ---- mask quad per kt: C-init rows = keys kt*16+4g+r ----
        f32x4 mb4[4];
#pragma unroll
        for (int kt = 0; kt < 4; ++kt)
#pragma unroll
            for (int r = 0; r < 4; ++r)
                mb4[kt][r] = mneg[kc + kt * 16 + g * 4 + r];

        // ---- K fragments, shared by both q-tiles ----
        bf16x8 bk[4][2];
#pragma unroll
        for (int kt = 0; kt < 4; ++kt) {
            const bf16* kr = &Ks[buf][(kt * 16 + l15) * 64];
            bk[kt][0] = *(const bf16x8*)(kr + rb0);
            bk[kt][1] = *(const bf16x8*)(kr + rb1);
        }

        // ---- QK^T both tiles; P fragments built in-register ----
        f32x4 S0[4], S1[4];
#pragma unroll
        for (int kt = 0; kt < 4; ++kt) {
            S0[kt] = MFMA16(bk[kt][0], aQ[0][0], mb4[kt]);
            S0[kt] = MFMA16(bk[kt][1], aQ[0][1], S0[kt]);
            S1[kt] = MFMA16(bk[kt][0], aQ[1][0], mb4[kt]);
            S1[kt] = MFMA16(bk[kt][1], aQ[1][1], S1[kt]);
        }

        bf16x8 pb0[2], pb1[2];
#pragma unroll
        for (int m = 0; m < 2; ++m) {
            union { bf16 hh[8]; bf16x8 v; } u0, u1;
#pragma unroll
            for (int j = 0; j < 4; ++j) {
                u0.hh[j]     = (bf16)__builtin_amdgcn_exp2f(S0[2 * m][j]);
                u0.hh[4 + j] = (bf16)__builtin_amdgcn_exp2f(S0[2 * m + 1][j]);
                u1.hh[j]     = (bf16)__builtin_amdgcn_exp2f(S1[2 * m][j]);
                u1.hh[4 + j] = (bf16)__builtin_amdgcn_exp2f(S1[2 * m + 1][j]);
            }
            pb0[m] = u0.v;
            pb1[m] = u1.v;
        }

        // ---- denominator on the matrix pipe ----
        lacc0 = MFMA16(ones, pb0[0], lacc0);
        lacc0 = MFMA16(ones, pb0[1], lacc0);
        lacc1 = MFMA16(ones, pb1[0], lacc1);
        lacc1 = MFMA16(ones, pb1[1], lacc1);

        // ---- PV: A = V^T (one b128 per (dt,m); vtg pre-permuted) ----
#pragma unroll
        for (int dt = 0; dt < 4; ++dt) {
            const bf16* vr = &Vt[buf][(dt * 16 + l15) * 64];
            bf16x8 vv0 = *(const bf16x8*)(vr + vb0);
            bf16x8 vv1 = *(const bf16x8*)(vr + vb1);
            o0[dt] = MFMA16(vv0, pb0[0], o0[dt]);
            o0[dt] = MFMA16(vv1, pb0[1], o0[dt]);
            o1[dt] = MFMA16(vv0, pb1[0], o1[dt]);
            o1[dt] = MFMA16(vv1, pb1[1], o1[dt]);
        }

        asm volatile("s_waitcnt vmcnt(0)" ::: "memory");  // prefetch landed
        __syncthreads();   // single barrier: buf^1 published, buf reads done
    }

    // ---- normalize + store O^T fragments ----
    const float inv0 = 1.0f / fmaxf(lacc0[0], 1e-30f);
    const float inv1 = 1.0f / fmaxf(lacc1[0], 1e-30f);
    bf16* op0 = O + (size_t)(b * 2048 + q0 + l15) * 1024 + h * 64 + g * 4;
    bf16* op1 = op0 + (size_t)64 * 1024;
#pragma unroll
    for (int dt = 0; dt < 4; ++dt) {
        union { bf16 hh[4]; ushort4 u; } s0, s1;
#pragma unroll
        for (int r = 0; r < 4; ++r) {
            s0.hh[r] = (bf16)(o0[dt][r] * inv0);
            s1.hh[r] = (bf16)(o1[dt][r] * inv1);
        }
        *(ushort4*)(op0 + dt * 16) = s0.u;
        *(ushort4*)(op1 + dt * 16) = s1.u;
    }
}

// ---------------------------------------------------------------------------
extern "C" void kernel_launch(void* const* d_in, const int* in_sizes, int n_in,
                              void* d_out, int out_size, void* d_ws, size_t ws_size,
                              hipStream_t stream)
{
    const float* x     = (const float*)d_in[0];
    const int*   mask  = (const int*)d_in[1];
    const float* w_qkv = (const float*)d_in[2];
    const float* b_qkv = (const float*)d_in[3];
    const float* w_out = (const float*)d_in[4];
    const float* b_out = (const float*)d_in[5];
    float* out = (float*)d_out;

    char* ws = (char*)d_ws;
    bf16* qkvb  = (bf16*)(ws);                 // 32 MiB: [8192][2048] (Q+K)
    bf16* Obuf  = (bf16*)(ws + 33554432);      // 16 MiB: [8192][1024]
    bf16* xb    = (bf16*)(ws + 50331648);      // 16 MiB: [8192][1024]
    bf16* wqkvT = (bf16*)(ws + 67108864);      //  6 MiB: [3072][1024]
    bf16* woutT = (bf16*)(ws + 73400320);      //  2 MiB: [1024][1024]
    bf16* vtg   = (bf16*)(ws + 75497472);      // 16 MiB: [64 bh][64 d][2048 n-perm]

    prep_kernel<<<dim3(9216), 256, 0, stream>>>(x, xb, w_qkv, wqkvT, w_out, woutT);
    gemm128x256_kernel<bf16><<<dim3(768), 512, 0, stream>>>(
        xb, wqkvT, b_qkv, qkvb, 8192, 2048, 1024, 1024, QSCALE, 12, vtg);
    attn_kernel<<<dim3(1024), 256, 0, stream>>>(qkvb, vtg, mask, Obuf);
    gemm128x256_kernel<float><<<dim3(256), 512, 0, stream>>>(
        Obuf, woutT, b_out, out, 8192, 1024, 1024, 0, 1.0f, 4, nullptr);
}